// Round 8
// baseline (2645.187 us; speedup 1.0000x reference)
//
#include <hip/hip_runtime.h>
#include <hip/hip_bf16.h>
#include <stdint.h>

#define BATCH 64
#define SLEN 128
#define TLEN 128
#define ENCD 512
#define DECD 512
#define EMBD 256
#define VOC  8000
#define HE   20
#define KX   1280      // EMB + DEC + ENC
#define NPAD 8064      // VOC padded to 63*128

typedef __attribute__((ext_vector_type(8))) short short8;
typedef __attribute__((ext_vector_type(8))) _Float16 half8v;
typedef __attribute__((ext_vector_type(4))) float f32x4;
typedef _Float16 h2 __attribute__((ext_vector_type(2)));

// ---------- helpers ----------
__device__ inline unsigned short f2bf(float f) {
  union { float f; uint32_t u; } v; v.f = f;
  uint32_t r = v.u + 0x7fff + ((v.u >> 16) & 1);
  return (unsigned short)(r >> 16);
}
__device__ inline unsigned short f16bits(float f) {
  union { _Float16 h; unsigned short u; } c; c.h = (_Float16)f; return c.u;
}
__device__ inline uint32_t pkh2(float a, float b) {
  union { h2 h; uint32_t u; } v;
  v.h = h2{(_Float16)a, (_Float16)b};
  return v.u;
}
__device__ inline float fdot2(uint32_t a, uint32_t b, float c) {
#if __has_builtin(__builtin_amdgcn_fdot2)
  union { uint32_t u; h2 h; } x, y; x.u = a; y.u = b;
  return __builtin_amdgcn_fdot2(x.h, y.h, c, false);
#else
  union { uint32_t u; h2 h; } x, y; x.u = a; y.u = b;
  return c + (float)x.h[0] * (float)y.h[0] + (float)x.h[1] * (float)y.h[1];
#endif
}
__device__ inline float eluf(float x) { return x > 0.f ? x : (expf(x) - 1.f); }

typedef const __attribute__((address_space(1))) unsigned int* gptr_t;
typedef __attribute__((address_space(3))) unsigned int* lptr_t;
__device__ inline void gload16(const void* g, void* l) {
  __builtin_amdgcn_global_load_lds((gptr_t)g, (lptr_t)l, 16, 0, 0);
}

// ---------- k_e1: E1t[b][h][s] = enc[b,s,:] @ We1[0:512,h] (transposed store) ----------
__global__ __launch_bounds__(256) void k_e1(const float* __restrict__ enc,
                                            const float* __restrict__ We1,
                                            float* __restrict__ E1) {
  __shared__ float rowbuf[4][ENCD];
  __shared__ float part[4][HE][2];
  int r0 = blockIdx.x * 4;
  int tid = threadIdx.x;
  for (int i = tid; i < 4 * ENCD; i += 256) {
    int rl = i >> 9, e = i & 511;
    rowbuf[rl][e] = enc[(size_t)(r0 + rl) * ENCD + e];
  }
  __syncthreads();
  if (tid < 160) {
    int kg = tid / 80, rem = tid % 80, rl = rem / 20, h = rem % 20;
    float acc = 0.f;
    for (int k = kg * 256; k < kg * 256 + 256; ++k)
      acc += rowbuf[rl][k] * We1[k * HE + h];
    part[rl][h][kg] = acc;
  }
  __syncthreads();
  if (tid < 80) {
    int rl = tid / 20, h = tid % 20;
    int r = r0 + rl, bb = r >> 7, ss = r & 127;
    E1[((size_t)bb * HE + h) * SLEN + ss] = part[rl][h][0] + part[rl][h][1];
  }
}

// ---------- k_tr_wout: W_out [1280][8000] f32 -> WoT [8064][1280] bf16 ----------
__global__ __launch_bounds__(256) void k_tr_wout(const float* __restrict__ Wo,
                                                 unsigned short* __restrict__ WoT) {
  __shared__ float tile[64][65];
  int n0 = blockIdx.x * 64, k0 = blockIdx.y * 64;
  int tid = threadIdx.x;
  for (int i = tid; i < 4096; i += 256) {
    int kk = i >> 6, nn = i & 63;
    int n = n0 + nn;
    tile[kk][nn] = (n < VOC) ? Wo[(size_t)(k0 + kk) * VOC + n] : 0.f;
  }
  __syncthreads();
  for (int i = tid; i < 4096; i += 256) {
    int nn = i >> 6, kk = i & 63;
    WoT[(size_t)(n0 + nn) * KX + k0 + kk] = f2bf(tile[kk][nn]);
  }
}

// ---------- k_tr_w: src rows [k0 .. k0+KN) of [*][512] f32 -> dst [512][KN] ----------
__global__ __launch_bounds__(256) void k_tr_w(const float* __restrict__ src,
                                              unsigned short* __restrict__ dst,
                                              int k0, int KN, int fmt) {
  __shared__ float tile[64][65];
  int n0 = blockIdx.x * 64, kt = blockIdx.y * 64;
  int tid = threadIdx.x;
  for (int i = tid; i < 4096; i += 256) {
    int kk = i >> 6, nn = i & 63;
    tile[kk][nn] = src[(size_t)(k0 + kt + kk) * 512 + n0 + nn];
  }
  __syncthreads();
  for (int i = tid; i < 4096; i += 256) {
    int nn = i >> 6, kk = i & 63;
    float v = tile[kk][nn];
    dst[(size_t)(n0 + nn) * KN + kt + kk] = fmt ? f2bf(v) : f16bits(v);
  }
}

// ---------- k_prep_wr: Wr rows 256..768 -> chunked f16 W2[(h*32+kc)*512+n][8] ----------
__global__ __launch_bounds__(256) void k_prep_wr(const float* __restrict__ Wr,
                                                 unsigned short* __restrict__ W2) {
  int i = blockIdx.x * 256 + threadIdx.x;
  int n = i & 511;
  int j = (i >> 9) & 7;
  int kc = (i >> 12) & 31;
  int h = (i >> 17) & 1;
  int k = h * 256 + kc * 8 + j;
  W2[(((size_t)(h * 32 + kc) * 512) + n) * 8 + j] = f16bits(Wr[(size_t)(256 + k) * 512 + n]);
}

// ---------- k_ench: enc f32 -> f16 flat [8192][512] ----------
__global__ __launch_bounds__(256) void k_ench(const float* __restrict__ enc,
                                              unsigned short* __restrict__ ench) {
  int i = (blockIdx.x * 256 + threadIdx.x) * 4;
  float4 v = *(const float4*)(enc + i);
  ushort4 o = { f16bits(v.x), f16bits(v.y), f16bits(v.z), f16bits(v.w) };
  *(ushort4*)(ench + i) = o;
}

// ---------- k_wh: wout f32 [8192][128] -> f16 ----------
__global__ __launch_bounds__(256) void k_wh(const float* __restrict__ wout,
                                            unsigned short* __restrict__ wh) {
  int i = (blockIdx.x * 256 + threadIdx.x) * 4;
  float4 v = *(const float4*)(wout + i);
  ushort4 o = { f16bits(v.x), f16bits(v.y), f16bits(v.z), f16bits(v.w) };
  *(ushort4*)(wh + i) = o;
}

// ---------- k_tr_encb: enc [b][s][e] f32 -> encTh [b][e][s] f16 ----------
__global__ __launch_bounds__(256) void k_tr_encb(const float* __restrict__ enc,
                                                 unsigned short* __restrict__ encT) {
  __shared__ float tile[64][65];
  int b = blockIdx.x, e0 = blockIdx.y * 64, s0 = blockIdx.z * 64;
  int tid = threadIdx.x;
  const float* eb = enc + (size_t)b * SLEN * ENCD;
  for (int i = tid; i < 4096; i += 256) {
    int ss = i >> 6, ee = i & 63;
    tile[ss][ee] = eb[(size_t)(s0 + ss) * ENCD + e0 + ee];
  }
  __syncthreads();
  unsigned short* ob = encT + (size_t)b * ENCD * SLEN;
  for (int i = tid; i < 4096; i += 256) {
    int ee = i >> 6, ss = i & 63;
    ob[(size_t)(e0 + ee) * SLEN + s0 + ss] = f16bits(tile[ss][ee]);
  }
}

// ---------- k_lc: X[t*B+b][0:256] = bf16(emb[lc]) ----------
__global__ __launch_bounds__(256) void k_lc(const int* __restrict__ ro,
                                            const float* __restrict__ emb,
                                            unsigned short* __restrict__ X) {
  int r = blockIdx.x;
  int t = r >> 6, b = r & 63;
  int lc = (t == 0) ? 0 : ro[b * TLEN + t - 1];
  lc = ((lc % VOC) + VOC) % VOC;
  X[(size_t)r * KX + threadIdx.x] = f2bf(emb[(size_t)lc * EMBD + threadIdx.x]);
}

// ---------- k_gs<MODE>: 128x128xK MFMA GEMM ----------
#define BM 128
#define BN 128
#define BK 64

template<int MODE>
__global__ __launch_bounds__(256) void k_gs(
    const unsigned short* __restrict__ A,
    const unsigned short* __restrict__ B,
    const float* __restrict__ bias,
    unsigned short* __restrict__ Cout)
{
  constexpr int As = (MODE == 0) ? KX : (MODE == 1 ? 512 : 128);
  constexpr int Bs = (MODE == 0) ? 256 : (MODE == 1 ? 512 : 128);
  constexpr int KT = (MODE == 0) ? 4 : (MODE == 1 ? 8 : 2);
  __shared__ __align__(16) unsigned short Asd[BM * BK];
  __shared__ __align__(16) unsigned short Bsd[BN * BK];
  int bx = blockIdx.x, by = blockIdx.y;
  int tid = threadIdx.x;
  int wid = tid >> 6, lane = tid & 63;
  int wr = wid >> 1, wc = wid & 1;

  f32x4 acc[4][4];
  for (int i = 0; i < 4; ++i)
    for (int j = 0; j < 4; ++j) acc[i][j] = (f32x4)0.f;

  const unsigned short* Abase = A + (size_t)by * BM * As;
  const unsigned short* Bbase = B + (size_t)bx * BN * Bs + (MODE == 2 ? (size_t)by * 512 * 128 : 0);

  for (int kt = 0; kt < KT; ++kt) {
    for (int j = 0; j < 4; ++j) {
      int c = tid + j * 256;
      int r = c >> 3, c16 = c & 7;
      int sk = c16 ^ (r & 7);
      gload16(Abase + (size_t)r * As + kt * BK + sk * 8, (char*)Asd + c * 16);
      gload16(Bbase + (size_t)r * Bs + kt * BK + sk * 8, (char*)Bsd + c * 16);
    }
    __syncthreads();
    for (int ks = 0; ks < 2; ++ks) {
      short8 af[4], bf[4];
      int kc = ks * 4 + (lane >> 4);
      for (int i = 0; i < 4; ++i) {
        int r = wr * 64 + i * 16 + (lane & 15);
        af[i] = *(const short8*)((const char*)Asd + r * 128 + ((kc ^ (r & 7)) * 16));
      }
      for (int j = 0; j < 4; ++j) {
        int r = wc * 64 + j * 16 + (lane & 15);
        bf[j] = *(const short8*)((const char*)Bsd + r * 128 + ((kc ^ (r & 7)) * 16));
      }
      for (int i = 0; i < 4; ++i)
        for (int j = 0; j < 4; ++j) {
          if constexpr (MODE == 0)
            acc[i][j] = __builtin_amdgcn_mfma_f32_16x16x32_bf16(af[i], bf[j], acc[i][j], 0, 0, 0);
          else
            acc[i][j] = __builtin_amdgcn_mfma_f32_16x16x32_f16(
                __builtin_bit_cast(half8v, af[i]), __builtin_bit_cast(half8v, bf[j]), acc[i][j], 0, 0, 0);
        }
    }
    __syncthreads();
  }

  int rl = lane >> 4, cl = lane & 15;
  for (int j = 0; j < 4; ++j) {
    int gn = bx * BN + wc * 64 + j * 16 + cl;
    for (int i = 0; i < 4; ++i) {
      for (int q = 0; q < 4; ++q) {
        int gm = by * BM + wr * 64 + i * 16 + rl * 4 + q;
        float v = acc[i][j][q];
        if constexpr (MODE == 0) {
          Cout[(size_t)gm * 512 + gn] = f16bits(v + bias[gn]);
        } else if constexpr (MODE == 1) {
          int bb = gm >> 7, s = gm & 127;
          Cout[(((size_t)(bb * 16 + (s >> 3)) * 512) + gn) * 8 + (s & 7)] = f16bits(v);
        } else {
          int tt = gm & 127, bb = gm >> 7;
          Cout[((size_t)tt * 64 + bb) * KX + 768 + gn] = f2bf(v);
        }
      }
    }
  }
}

// ---------- k_recur: per-wave LDS-ring streaming recurrence ----------
// Phase A: waves 0..13 stream 32 W2 rows each, wave 14 streams 64 (n=448..511
// full columns), each via a private 8-slot x 1KB LDS ring filled by
// global_load_lds (fire-and-forget) and drained with counted vmcnt waits.
// Wave 15 runs the attention chain at raised priority.
// Phase B: waves 0..7 stream encW2 rows (issued pre-barrier) the same way.
#define WAITV(n) asm volatile("s_waitcnt vmcnt(" #n ")" ::: "memory")
#define ISSA(J) gload16((const char*)W2 + (((size_t)(hbase + (J)) * 512 + mn) * 16), \
                        (char*)ring + wv_ * 8192 + ((J) & 7) * 1024)
#define CONSA(J, WN, R) { WAITV(WN); \
  uint4 tv = ring[wv_][(J) & 7][lane]; uint4 xv = hp4[hbase + (J)]; \
  a0 = fdot2(tv.x, xv.x, a0); a1 = fdot2(tv.y, xv.y, a1); \
  a2 = fdot2(tv.z, xv.z, a2); a3 = fdot2(tv.w, xv.w, a3); \
  if ((J) + 8 < (R)) ISSA((J) + 8); }
#define CA8(J, R) CONSA(J,7,R) CONSA((J)+1,7,R) CONSA((J)+2,7,R) CONSA((J)+3,7,R) \
                  CONSA((J)+4,7,R) CONSA((J)+5,7,R) CONSA((J)+6,7,R) CONSA((J)+7,7,R)
#define ISSB(J) gload16((const char*)encW2b + (((size_t)(J) * 512 + tid) * 16), \
                        (char*)ring + wv_ * 8192 + ((J) & 7) * 1024)
#define CONSB(J, WN) { WAITV(WN); \
  uint4 ev = ring[wv_][(J) & 7][lane]; uint4 wq = ((const uint4*)wpairS)[J]; \
  c0 = fdot2(ev.x, wq.x, c0); c1 = fdot2(ev.y, wq.y, c1); \
  c2 = fdot2(ev.z, wq.z, c2); c3 = fdot2(ev.w, wq.w, c3); \
  if ((J) + 8 < 16) ISSB((J) + 8); }

__global__ __launch_bounds__(1024) void k_recur(
    const float* __restrict__ We1,     // [1024][20]
    const float* __restrict__ be1,
    const float* __restrict__ We2,
    const float* __restrict__ be2,
    const uint4* __restrict__ W2,      // chunked f16, 32768 uint4
    const uint4* __restrict__ encW2,   // [64][16][512] uint4
    const unsigned short* __restrict__ Remb, // f16 [8192][512] (brnn folded)
    const float* __restrict__ E1g,     // [64][20][128]
    unsigned short* __restrict__ X,    // [8192][1280] bf16
    float* __restrict__ wout)          // [64][128][128]
{
  __shared__ __align__(16) uint4 ring[16][8][64];  // 128 KB: per-wave staging rings
  __shared__ uint32_t E1p[HE][SLEN / 2];           // 5 KB (f16 pairs)
  __shared__ uint32_t w1p[HE][257];                // 20.6 KB
  __shared__ uint32_t hpair[DECD / 2];             // 1 KB
  __shared__ uint32_t wpairS[SLEN / 2];            // 256 B
  __shared__ float ph[2][DECD];                    // 4 KB
  __shared__ float be1s[HE], w2s[HE];
  __shared__ float be2s;

  int b = blockIdx.x, tid = threadIdx.x;
  const uint4* encW2b = encW2 + (size_t)b * 8192;

  for (int i = tid; i < HE * (SLEN / 2); i += 1024) {
    int h = i >> 6, p = i & 63;
    const float* ebase = E1g + ((size_t)b * HE + h) * SLEN;
    ((uint32_t*)E1p)[i] = pkh2(ebase[2 * p], ebase[2 * p + 1]);
  }
  for (int i = tid; i < HE * 256; i += 1024) {
    int h = i >> 8, p = i & 255;
    w1p[h][p] = pkh2(We1[(size_t)(ENCD + 2 * p) * HE + h],
                     We1[(size_t)(ENCD + 2 * p + 1) * HE + h]);
  }
  for (int i = tid; i < DECD / 2; i += 1024) hpair[i] = 0;
  for (int i = tid; i < DECD; i += 1024) { ph[0][i] = 0.f; ph[1][i] = 0.f; }
  if (tid < HE) { be1s[tid] = be1[tid]; w2s[tid] = We2[tid]; }
  if (tid == 0) be2s = be2[0];
  __syncthreads();

  const int lane = tid & 63;
  const int wv_ = tid >> 6;
  int mn, mh0;
  if (tid < 448)      { mn = tid;               mh0 = 0; }
  else if (tid < 896) { mn = tid - 448;         mh0 = 1; }
  else                { mn = 448 + lane;        mh0 = 0; }  // waves 14,15
  const uint4* hp4 = (const uint4*)hpair;
  const int hbase = mh0 * 32;

  // attention lane roles (wave 15)
  int ah = lane % 20, aseg = lane / 20;
  int q0 = aseg * 86;
  int q1 = (aseg == 2) ? 256 : q0 + 86;
  if (aseg >= 3) { q0 = 0; q1 = 0; }

  for (int t = 0; t < TLEN; ++t) {
    const int rowr = t * BATCH + b;

    if (wv_ == 15) {
      // ---------- phase A: attention chain, single wave, raised priority ----------
      __builtin_amdgcn_s_setprio(1);
      float p0 = 0, p1 = 0;
      for (int q = q0; q < q1; q += 2) {
        p0 = fdot2(w1p[ah][q], hpair[q], p0);
        p1 = fdot2(w1p[ah][q + 1], hpair[q + 1], p1);
      }
      float p = p0 + p1;
      float pa = __shfl(p, lane + 20);
      float pb = __shfl(p, lane + 40);
      float edv = p + pa + pb + ((lane < HE) ? be1s[lane] : 0.f);
      float e0a = 0.f, e1a = 0.f;
      #pragma unroll
      for (int h = 0; h < HE; ++h) {
        union { uint32_t u; h2 hh; } e; e.u = E1p[h][lane];
        float ed = __shfl(edv, h);
        e0a += eluf((float)e.hh[0] + ed) * w2s[h];
        e1a += eluf((float)e.hh[1] + ed) * w2s[h];
      }
      float s0 = expf(eluf(e0a + be2s));
      float s1 = expf(eluf(e1a + be2s));
      float tot = s0 + s1;
      #pragma unroll
      for (int o = 1; o < 64; o <<= 1) tot += __shfl_xor(tot, o);
      float inv = 1.f / tot;
      float w0 = s0 * inv, w1 = s1 * inv;
      wpairS[lane] = pkh2(w0, w1);
      float2 wv2 = { w0, w1 };
      *(float2*)(wout + ((size_t)b * TLEN + t) * SLEN + 2 * lane) = wv2;
      __builtin_amdgcn_s_setprio(0);
    } else if (wv_ == 14) {
      // ---------- phase A: full columns n=448..511, 64 rows through the ring ----------
      float a0 = 0, a1 = 0, a2 = 0, a3 = 0;
      ISSA(0); ISSA(1); ISSA(2); ISSA(3); ISSA(4); ISSA(5); ISSA(6); ISSA(7);
      CA8(0, 64) CA8(8, 64) CA8(16, 64) CA8(24, 64)
      CA8(32, 64) CA8(40, 64) CA8(48, 64)
      CONSA(56, 7, 64) CONSA(57, 6, 64) CONSA(58, 5, 64) CONSA(59, 4, 64)
      CONSA(60, 3, 64) CONSA(61, 2, 64) CONSA(62, 1, 64) CONSA(63, 0, 64)
      ph[0][mn] = (a0 + a1) + (a2 + a3);
    } else {
      // ---------- phase A: one half-column (32 rows) through the ring ----------
      float a0 = 0, a1 = 0, a2 = 0, a3 = 0;
      ISSA(0); ISSA(1); ISSA(2); ISSA(3); ISSA(4); ISSA(5); ISSA(6); ISSA(7);
      CA8(0, 32) CA8(8, 32) CA8(16, 32)
      CONSA(24, 7, 32) CONSA(25, 6, 32) CONSA(26, 5, 32) CONSA(27, 4, 32)
      CONSA(28, 3, 32) CONSA(29, 2, 32) CONSA(30, 1, 32) CONSA(31, 0, 32)
      ph[mh0][mn] = (a0 + a1) + (a2 + a3);
      if (wv_ < 8) {   // pre-issue phase-B ctx rows; they fly across the barrier
        ISSB(0); ISSB(1); ISSB(2); ISSB(3); ISSB(4); ISSB(5); ISSB(6); ISSB(7);
      }
    }
    __syncthreads();

    // ---------- phase B: ctx (ring-streamed encW2) + combine ----------
    if (tid < 512) {
      float rpre;
      {
        union { unsigned short u; _Float16 f; } c;
        c.u = Remb[(size_t)rowr * 512 + tid];
        rpre = (float)c.f;
      }
      float c0 = 0, c1 = 0, c2 = 0, c3 = 0;
      CONSB(0, 7) CONSB(1, 7) CONSB(2, 7) CONSB(3, 7) CONSB(4, 7)
      CONSB(5, 7) CONSB(6, 7) CONSB(7, 7) CONSB(8, 7)
      CONSB(9, 6) CONSB(10, 5) CONSB(11, 4) CONSB(12, 3)
      CONSB(13, 2) CONSB(14, 1) CONSB(15, 0)
      int n = tid;
      float v = rpre + ph[0][n] + ph[1][n] + (c0 + c1) + (c2 + c3);
      float aa = eluf(v);
      X[(size_t)rowr * KX + 256 + n] = f2bf(aa);
      float bb = __shfl_down(aa, 1);
      if (!(n & 1)) hpair[n >> 1] = pkh2(aa, bb);
    }
    __syncthreads();
  }
}

// ---------- k_gemm: out = elu(X @ WoT^T + b_out), M=8192 N=8000 K=1280 ----------
// linear grid 4032 = 63x64, bijective XCD swizzle (4032 % 8 == 0)
__global__ __launch_bounds__(256) void k_gemm(
    const unsigned short* __restrict__ Xb,
    const unsigned short* __restrict__ WoT,
    const float* __restrict__ bout,
    float* __restrict__ out)
{
  __shared__ __align__(16) unsigned short As[BM * BK];
  __shared__ __align__(16) unsigned short Bs[BN * BK];
  int bid = blockIdx.x;
  int swz = (bid & 7) * 504 + (bid >> 3);
  int bx = swz % 63;
  int by = swz / 63;
  int tid = threadIdx.x;
  int wid = tid >> 6, lane = tid & 63;
  int wr = wid >> 1, wc = wid & 1;

  f32x4 acc[4][4];
  for (int i = 0; i < 4; ++i)
    for (int j = 0; j < 4; ++j) acc[i][j] = (f32x4)0.f;

  const unsigned short* Abase = Xb + (size_t)by * BM * KX;
  const unsigned short* Bbase = WoT + (size_t)bx * BN * KX;

  for (int kt = 0; kt < KX / BK; ++kt) {
    for (int j = 0; j < 4; ++j) {
      int c = tid + j * 256;
      int r = c >> 3, c16 = c & 7;
      int sk = c16 ^ (r & 7);
      gload16(Abase + (size_t)r * KX + kt * BK + sk * 8, (char*)As + c * 16);
      gload16(Bbase + (size_t)r * KX + kt * BK + sk * 8, (char*)Bs + c * 16);
    }
    __syncthreads();
    for (int ks = 0; ks < 2; ++ks) {
      short8 af[4], bf[4];
      int kc = ks * 4 + (lane >> 4);
      for (int i = 0; i < 4; ++i) {
        int r = wr * 64 + i * 16 + (lane & 15);
        af[i] = *(const short8*)((const char*)As + r * 128 + ((kc ^ (r & 7)) * 16));
      }
      for (int j = 0; j < 4; ++j) {
        int r = wc * 64 + j * 16 + (lane & 15);
        bf[j] = *(const short8*)((const char*)Bs + r * 128 + ((kc ^ (r & 7)) * 16));
      }
      for (int i = 0; i < 4; ++i)
        for (int j = 0; j < 4; ++j)
          acc[i][j] = __builtin_amdgcn_mfma_f32_16x16x32_bf16(af[i], bf[j], acc[i][j], 0, 0, 0);
    }
    __syncthreads();
  }

  int rl = lane >> 4, cl = lane & 15;
  for (int j = 0; j < 4; ++j) {
    int gn = bx * BN + wc * 64 + j * 16 + cl;
    if (gn >= VOC) continue;
    float bv = bout[gn];
    for (int i = 0; i < 4; ++i) {
      for (int q = 0; q < 4; ++q) {
        int gm = by * BM + wr * 64 + i * 16 + rl * 4 + q;
        int tt = gm >> 6, bb = gm & 63;
        float v = acc[i][j][q] + bv;
        v = v > 0.f ? v : (expf(v) - 1.f);
        out[((size_t)bb * TLEN + tt) * VOC + gn] = v;
      }
    }
  }
}

// ---------- launch ----------
extern "C" void kernel_launch(void* const* d_in, const int* in_sizes, int n_in,
                              void* d_out, int out_size, void* d_ws, size_t ws_size,
                              hipStream_t stream) {
  const float* enc  = (const float*)d_in[0];
  const int*   ro   = (const int*)d_in[1];
  const float* We1  = (const float*)d_in[2];
  const float* be1  = (const float*)d_in[3];
  const float* We2  = (const float*)d_in[4];
  const float* be2  = (const float*)d_in[5];
  const float* emb  = (const float*)d_in[6];
  const float* Wr   = (const float*)d_in[7];
  const float* brnn = (const float*)d_in[8];
  const float* Wo   = (const float*)d_in[9];
  const float* bo   = (const float*)d_in[10];

  char* ws = (char*)d_ws;
  unsigned short* X     = (unsigned short*)(ws);                 // 20,971,520
  unsigned short* WoT   = (unsigned short*)(ws + 20971520);      // 20,643,840
  unsigned short* W2    = (unsigned short*)(ws + 41615360);      //    524,288
  unsigned short* WembT = (unsigned short*)(ws + 42139648);      //    262,144
  unsigned short* WctxT = (unsigned short*)(ws + 42401792);      //    524,288
  unsigned short* ench  = (unsigned short*)(ws + 42926080);      //  8,388,608  (reused: encTh)
  float*          E1    = (float*)(ws + 51314688);               //    655,360
  unsigned short* Remb  = (unsigned short*)(ws + 51970048);      //  8,388,608  (reused: wh)
  unsigned short* encW2 = (unsigned short*)(ws + 60358656);      //  8,388,608
  unsigned short* encTh = ench;
  unsigned short* wh    = Remb;

  float* outs = (float*)d_out;
  float* wout = (float*)d_out + (size_t)BATCH * TLEN * VOC;

  // parallel precompute
  k_lc     <<<dim3(8192),     256, 0, stream>>>(ro, emb, X);
  k_e1     <<<dim3(2048),     256, 0, stream>>>(enc, We1, E1);
  k_tr_wout<<<dim3(126, 20),  256, 0, stream>>>(Wo, WoT);
  k_tr_w   <<<dim3(8, 4),     256, 0, stream>>>(Wr, WembT, 0, 256, 1);
  k_tr_w   <<<dim3(8, 8),     256, 0, stream>>>(Wr, WctxT, 768, 512, 0);
  k_prep_wr<<<dim3(1024),     256, 0, stream>>>(Wr, W2);
  k_ench   <<<dim3(4096),     256, 0, stream>>>(enc, ench);
  k_gs<0>  <<<dim3(4, 64),    256, 0, stream>>>(X, WembT, brnn, Remb);
  k_gs<1>  <<<dim3(4, 64),    256, 0, stream>>>(ench, WctxT, brnn, encW2);
  // sequential core
  k_recur  <<<dim3(64),      1024, 0, stream>>>(We1, be1, We2, be2,
                                                (const uint4*)W2, (const uint4*)encW2,
                                                Remb, E1, X, wout);
  // post: ctx fill + big GEMM
  k_wh     <<<dim3(1024),     256, 0, stream>>>(wout, wh);
  k_tr_encb<<<dim3(64, 8, 2), 256, 0, stream>>>(enc, encTh);
  k_gs<2>  <<<dim3(4, 64),    256, 0, stream>>>(wh, encTh, brnn, X);
  k_gemm   <<<dim3(4032),     256, 0, stream>>>(X, WoT, bo, outs);
  (void)in_sizes; (void)n_in; (void)out_size; (void)ws_size;
}

// Round 9
// 2162.479 us; speedup vs baseline: 1.2232x; 1.2232x over previous
//
#include <hip/hip_runtime.h>
#include <hip/hip_bf16.h>
#include <stdint.h>

#define BATCH 64
#define SLEN 128
#define TLEN 128
#define ENCD 512
#define DECD 512
#define EMBD 256
#define VOC  8000
#define HE   20
#define KX   1280      // EMB + DEC + ENC
#define NPAD 8064      // VOC padded to 63*128

typedef __attribute__((ext_vector_type(8))) short short8;
typedef __attribute__((ext_vector_type(8))) _Float16 half8v;
typedef __attribute__((ext_vector_type(4))) float f32x4;
typedef _Float16 h2 __attribute__((ext_vector_type(2)));

// ---------- helpers ----------
__device__ inline unsigned short f2bf(float f) {
  union { float f; uint32_t u; } v; v.f = f;
  uint32_t r = v.u + 0x7fff + ((v.u >> 16) & 1);
  return (unsigned short)(r >> 16);
}
__device__ inline unsigned short f16bits(float f) {
  union { _Float16 h; unsigned short u; } c; c.h = (_Float16)f; return c.u;
}
__device__ inline uint32_t pkh2(float a, float b) {
  union { h2 h; uint32_t u; } v;
  v.h = h2{(_Float16)a, (_Float16)b};
  return v.u;
}
__device__ inline float fdot2(uint32_t a, uint32_t b, float c) {
#if __has_builtin(__builtin_amdgcn_fdot2)
  union { uint32_t u; h2 h; } x, y; x.u = a; y.u = b;
  return __builtin_amdgcn_fdot2(x.h, y.h, c, false);
#else
  union { uint32_t u; h2 h; } x, y; x.u = a; y.u = b;
  return c + (float)x.h[0] * (float)y.h[0] + (float)x.h[1] * (float)y.h[1];
#endif
}
__device__ inline float eluf(float x) { return x > 0.f ? x : (expf(x) - 1.f); }

typedef const __attribute__((address_space(1))) unsigned int* gptr_t;
typedef __attribute__((address_space(3))) unsigned int* lptr_t;
__device__ inline void gload16(const void* g, void* l) {
  __builtin_amdgcn_global_load_lds((gptr_t)g, (lptr_t)l, 16, 0, 0);
}

// ---------- k_e1: E1t[b][h][s] = enc[b,s,:] @ We1[0:512,h] (transposed store) ----------
__global__ __launch_bounds__(256) void k_e1(const float* __restrict__ enc,
                                            const float* __restrict__ We1,
                                            float* __restrict__ E1) {
  __shared__ float rowbuf[4][ENCD];
  __shared__ float part[4][HE][2];
  int r0 = blockIdx.x * 4;
  int tid = threadIdx.x;
  for (int i = tid; i < 4 * ENCD; i += 256) {
    int rl = i >> 9, e = i & 511;
    rowbuf[rl][e] = enc[(size_t)(r0 + rl) * ENCD + e];
  }
  __syncthreads();
  if (tid < 160) {
    int kg = tid / 80, rem = tid % 80, rl = rem / 20, h = rem % 20;
    float acc = 0.f;
    for (int k = kg * 256; k < kg * 256 + 256; ++k)
      acc += rowbuf[rl][k] * We1[k * HE + h];
    part[rl][h][kg] = acc;
  }
  __syncthreads();
  if (tid < 80) {
    int rl = tid / 20, h = tid % 20;
    int r = r0 + rl, bb = r >> 7, ss = r & 127;
    E1[((size_t)bb * HE + h) * SLEN + ss] = part[rl][h][0] + part[rl][h][1];
  }
}

// ---------- k_tr_wout: W_out [1280][8000] f32 -> WoT [8064][1280] bf16 ----------
__global__ __launch_bounds__(256) void k_tr_wout(const float* __restrict__ Wo,
                                                 unsigned short* __restrict__ WoT) {
  __shared__ float tile[64][65];
  int n0 = blockIdx.x * 64, k0 = blockIdx.y * 64;
  int tid = threadIdx.x;
  for (int i = tid; i < 4096; i += 256) {
    int kk = i >> 6, nn = i & 63;
    int n = n0 + nn;
    tile[kk][nn] = (n < VOC) ? Wo[(size_t)(k0 + kk) * VOC + n] : 0.f;
  }
  __syncthreads();
  for (int i = tid; i < 4096; i += 256) {
    int nn = i >> 6, kk = i & 63;
    WoT[(size_t)(n0 + nn) * KX + k0 + kk] = f2bf(tile[kk][nn]);
  }
}

// ---------- k_tr_w: src rows [k0 .. k0+KN) of [*][512] f32 -> dst [512][KN] ----------
__global__ __launch_bounds__(256) void k_tr_w(const float* __restrict__ src,
                                              unsigned short* __restrict__ dst,
                                              int k0, int KN, int fmt) {
  __shared__ float tile[64][65];
  int n0 = blockIdx.x * 64, kt = blockIdx.y * 64;
  int tid = threadIdx.x;
  for (int i = tid; i < 4096; i += 256) {
    int kk = i >> 6, nn = i & 63;
    tile[kk][nn] = src[(size_t)(k0 + kt + kk) * 512 + n0 + nn];
  }
  __syncthreads();
  for (int i = tid; i < 4096; i += 256) {
    int nn = i >> 6, kk = i & 63;
    float v = tile[kk][nn];
    dst[(size_t)(n0 + nn) * KN + kt + kk] = fmt ? f2bf(v) : f16bits(v);
  }
}

// ---------- k_prep_wr: Wr rows 256..768 -> chunked f16 W2[(h*32+kc)*512+n][8] ----------
__global__ __launch_bounds__(256) void k_prep_wr(const float* __restrict__ Wr,
                                                 unsigned short* __restrict__ W2) {
  int i = blockIdx.x * 256 + threadIdx.x;
  int n = i & 511;
  int j = (i >> 9) & 7;
  int kc = (i >> 12) & 31;
  int h = (i >> 17) & 1;
  int k = h * 256 + kc * 8 + j;
  W2[(((size_t)(h * 32 + kc) * 512) + n) * 8 + j] = f16bits(Wr[(size_t)(256 + k) * 512 + n]);
}

// ---------- k_ench: enc f32 -> f16 flat [8192][512] ----------
__global__ __launch_bounds__(256) void k_ench(const float* __restrict__ enc,
                                              unsigned short* __restrict__ ench) {
  int i = (blockIdx.x * 256 + threadIdx.x) * 4;
  float4 v = *(const float4*)(enc + i);
  ushort4 o = { f16bits(v.x), f16bits(v.y), f16bits(v.z), f16bits(v.w) };
  *(ushort4*)(ench + i) = o;
}

// ---------- k_wh: wout f32 [8192][128] -> f16 ----------
__global__ __launch_bounds__(256) void k_wh(const float* __restrict__ wout,
                                            unsigned short* __restrict__ wh) {
  int i = (blockIdx.x * 256 + threadIdx.x) * 4;
  float4 v = *(const float4*)(wout + i);
  ushort4 o = { f16bits(v.x), f16bits(v.y), f16bits(v.z), f16bits(v.w) };
  *(ushort4*)(wh + i) = o;
}

// ---------- k_tr_encb: enc [b][s][e] f32 -> encTh [b][e][s] f16 ----------
__global__ __launch_bounds__(256) void k_tr_encb(const float* __restrict__ enc,
                                                 unsigned short* __restrict__ encT) {
  __shared__ float tile[64][65];
  int b = blockIdx.x, e0 = blockIdx.y * 64, s0 = blockIdx.z * 64;
  int tid = threadIdx.x;
  const float* eb = enc + (size_t)b * SLEN * ENCD;
  for (int i = tid; i < 4096; i += 256) {
    int ss = i >> 6, ee = i & 63;
    tile[ss][ee] = eb[(size_t)(s0 + ss) * ENCD + e0 + ee];
  }
  __syncthreads();
  unsigned short* ob = encT + (size_t)b * ENCD * SLEN;
  for (int i = tid; i < 4096; i += 256) {
    int ee = i >> 6, ss = i & 63;
    ob[(size_t)(e0 + ee) * SLEN + s0 + ss] = f16bits(tile[ss][ee]);
  }
}

// ---------- k_lc: X[t*B+b][0:256] = bf16(emb[lc]) ----------
__global__ __launch_bounds__(256) void k_lc(const int* __restrict__ ro,
                                            const float* __restrict__ emb,
                                            unsigned short* __restrict__ X) {
  int r = blockIdx.x;
  int t = r >> 6, b = r & 63;
  int lc = (t == 0) ? 0 : ro[b * TLEN + t - 1];
  lc = ((lc % VOC) + VOC) % VOC;
  X[(size_t)r * KX + threadIdx.x] = f2bf(emb[(size_t)lc * EMBD + threadIdx.x]);
}

// ---------- k_gs<MODE>: 128x128xK MFMA GEMM ----------
#define BM 128
#define BN 128
#define BK 64

template<int MODE>
__global__ __launch_bounds__(256) void k_gs(
    const unsigned short* __restrict__ A,
    const unsigned short* __restrict__ B,
    const float* __restrict__ bias,
    unsigned short* __restrict__ Cout)
{
  constexpr int As = (MODE == 0) ? KX : (MODE == 1 ? 512 : 128);
  constexpr int Bs = (MODE == 0) ? 256 : (MODE == 1 ? 512 : 128);
  constexpr int KT = (MODE == 0) ? 4 : (MODE == 1 ? 8 : 2);
  __shared__ __align__(16) unsigned short Asd[BM * BK];
  __shared__ __align__(16) unsigned short Bsd[BN * BK];
  int bx = blockIdx.x, by = blockIdx.y;
  int tid = threadIdx.x;
  int wid = tid >> 6, lane = tid & 63;
  int wr = wid >> 1, wc = wid & 1;

  f32x4 acc[4][4];
  for (int i = 0; i < 4; ++i)
    for (int j = 0; j < 4; ++j) acc[i][j] = (f32x4)0.f;

  const unsigned short* Abase = A + (size_t)by * BM * As;
  const unsigned short* Bbase = B + (size_t)bx * BN * Bs + (MODE == 2 ? (size_t)by * 512 * 128 : 0);

  for (int kt = 0; kt < KT; ++kt) {
    for (int j = 0; j < 4; ++j) {
      int c = tid + j * 256;
      int r = c >> 3, c16 = c & 7;
      int sk = c16 ^ (r & 7);
      gload16(Abase + (size_t)r * As + kt * BK + sk * 8, (char*)Asd + c * 16);
      gload16(Bbase + (size_t)r * Bs + kt * BK + sk * 8, (char*)Bsd + c * 16);
    }
    __syncthreads();
    for (int ks = 0; ks < 2; ++ks) {
      short8 af[4], bf[4];
      int kc = ks * 4 + (lane >> 4);
      for (int i = 0; i < 4; ++i) {
        int r = wr * 64 + i * 16 + (lane & 15);
        af[i] = *(const short8*)((const char*)Asd + r * 128 + ((kc ^ (r & 7)) * 16));
      }
      for (int j = 0; j < 4; ++j) {
        int r = wc * 64 + j * 16 + (lane & 15);
        bf[j] = *(const short8*)((const char*)Bsd + r * 128 + ((kc ^ (r & 7)) * 16));
      }
      for (int i = 0; i < 4; ++i)
        for (int j = 0; j < 4; ++j) {
          if constexpr (MODE == 0)
            acc[i][j] = __builtin_amdgcn_mfma_f32_16x16x32_bf16(af[i], bf[j], acc[i][j], 0, 0, 0);
          else
            acc[i][j] = __builtin_amdgcn_mfma_f32_16x16x32_f16(
                __builtin_bit_cast(half8v, af[i]), __builtin_bit_cast(half8v, bf[j]), acc[i][j], 0, 0, 0);
        }
    }
    __syncthreads();
  }

  int rl = lane >> 4, cl = lane & 15;
  for (int j = 0; j < 4; ++j) {
    int gn = bx * BN + wc * 64 + j * 16 + cl;
    for (int i = 0; i < 4; ++i) {
      for (int q = 0; q < 4; ++q) {
        int gm = by * BM + wr * 64 + i * 16 + rl * 4 + q;
        float v = acc[i][j][q];
        if constexpr (MODE == 0) {
          Cout[(size_t)gm * 512 + gn] = f16bits(v + bias[gn]);
        } else if constexpr (MODE == 1) {
          int bb = gm >> 7, s = gm & 127;
          Cout[(((size_t)(bb * 16 + (s >> 3)) * 512) + gn) * 8 + (s & 7)] = f16bits(v);
        } else {
          int tt = gm & 127, bb = gm >> 7;
          Cout[((size_t)tt * 64 + bb) * KX + 768 + gn] = f2bf(v);
        }
      }
    }
  }
}

// ---------- k_recur: round-7 structure, deep alternating load pipeline ----------
// waves 0..13: stream half-columns (4 groups of 8 chunks), alternating A/B
//              register buffers, no copies, loads inside the branch.
// wave 14:     full columns n=448..511 (8 groups).
// wave 15:     attention chain at raised priority.
#define LOAD8(BUF, G) { _Pragma("unroll") \
  for (int j = 0; j < 8; ++j) BUF[j] = Wp[(size_t)((G) * 8 + j) * 512]; }
#define CONS8(BUF, G) { _Pragma("unroll") \
  for (int j = 0; j < 8; ++j) { \
    uint4 wv = BUF[j]; uint4 xv = hp4[hbase + (G) * 8 + j]; \
    a0 = fdot2(wv.x, xv.x, a0); a1 = fdot2(wv.y, xv.y, a1); \
    a2 = fdot2(wv.z, xv.z, a2); a3 = fdot2(wv.w, xv.w, a3); } }

__global__ __launch_bounds__(1024, 4) void k_recur(
    const float* __restrict__ We1,     // [1024][20]
    const float* __restrict__ be1,
    const float* __restrict__ We2,
    const float* __restrict__ be2,
    const uint4* __restrict__ W2,      // chunked f16, 32768 uint4
    const uint4* __restrict__ encW2,   // [64][16][512] uint4
    const unsigned short* __restrict__ Remb, // f16 [8192][512] (brnn folded)
    const float* __restrict__ E1g,     // [64][20][128]
    unsigned short* __restrict__ X,    // [8192][1280] bf16
    float* __restrict__ wout)          // [64][128][128]
{
  __shared__ __align__(16) uint4 el[16][512];   // 128 KB: encW2 slice (static)
  __shared__ uint32_t E1p[HE][SLEN / 2];        // 5 KB (f16 pairs)
  __shared__ uint32_t w1p[HE][257];             // 20.6 KB
  __shared__ uint32_t hpair[DECD / 2];          // 1 KB
  __shared__ uint32_t wpairS[SLEN / 2];         // 256 B
  __shared__ float ph[2][DECD];                 // 4 KB
  __shared__ float be1s[HE], w2s[HE];
  __shared__ float be2s;

  int b = blockIdx.x, tid = threadIdx.x;

  for (int i = tid; i < 16 * 512; i += 1024) ((uint4*)el)[i] = encW2[(size_t)b * 8192 + i];
  for (int i = tid; i < HE * (SLEN / 2); i += 1024) {
    int h = i >> 6, p = i & 63;
    const float* ebase = E1g + ((size_t)b * HE + h) * SLEN;
    ((uint32_t*)E1p)[i] = pkh2(ebase[2 * p], ebase[2 * p + 1]);
  }
  for (int i = tid; i < HE * 256; i += 1024) {
    int h = i >> 8, p = i & 255;
    w1p[h][p] = pkh2(We1[(size_t)(ENCD + 2 * p) * HE + h],
                     We1[(size_t)(ENCD + 2 * p + 1) * HE + h]);
  }
  for (int i = tid; i < DECD / 2; i += 1024) hpair[i] = 0;
  for (int i = tid; i < DECD; i += 1024) { ph[0][i] = 0.f; ph[1][i] = 0.f; }
  if (tid < HE) { be1s[tid] = be1[tid]; w2s[tid] = We2[tid]; }
  if (tid == 0) be2s = be2[0];
  __syncthreads();

  const int lane = tid & 63;
  const int wv_ = tid >> 6;
  int mn, mh0;
  if (tid < 448)      { mn = tid;        mh0 = 0; }
  else if (tid < 896) { mn = tid - 448;  mh0 = 1; }
  else                { mn = 448 + lane; mh0 = 0; }   // waves 14,15
  const uint4* Wp = W2 + (size_t)(mh0 * 32) * 512 + mn;
  const uint4* hp4 = (const uint4*)hpair;
  const int hbase = mh0 * 32;

  // attention lane roles (wave 15)
  int ah = lane % 20, aseg = lane / 20;
  int q0 = aseg * 86;
  int q1 = (aseg == 2) ? 256 : q0 + 86;
  if (aseg >= 3) { q0 = 0; q1 = 0; }

  for (int t = 0; t < TLEN; ++t) {
    const int rowr = t * BATCH + b;
    float rpre = 0.f;

    if (wv_ == 15) {
      // ---------- phase A: attention chain, single wave, raised priority ----------
      __builtin_amdgcn_s_setprio(1);
      float p0 = 0, p1 = 0;
      for (int q = q0; q < q1; q += 2) {
        p0 = fdot2(w1p[ah][q], hpair[q], p0);
        p1 = fdot2(w1p[ah][q + 1], hpair[q + 1], p1);
      }
      float p = p0 + p1;
      float pa = __shfl(p, lane + 20);
      float pb = __shfl(p, lane + 40);
      float edv = p + pa + pb + ((lane < HE) ? be1s[lane] : 0.f);
      float e0a = 0.f, e1a = 0.f;
      #pragma unroll
      for (int h = 0; h < HE; ++h) {
        union { uint32_t u; h2 hh; } e; e.u = E1p[h][lane];
        float ed = __shfl(edv, h);
        e0a += eluf((float)e.hh[0] + ed) * w2s[h];
        e1a += eluf((float)e.hh[1] + ed) * w2s[h];
      }
      float s0 = expf(eluf(e0a + be2s));
      float s1 = expf(eluf(e1a + be2s));
      float tot = s0 + s1;
      #pragma unroll
      for (int o = 1; o < 64; o <<= 1) tot += __shfl_xor(tot, o);
      float inv = 1.f / tot;
      float w0 = s0 * inv, w1 = s1 * inv;
      wpairS[lane] = pkh2(w0, w1);
      float2 wv2 = { w0, w1 };
      *(float2*)(wout + ((size_t)b * TLEN + t) * SLEN + 2 * lane) = wv2;
      __builtin_amdgcn_s_setprio(0);
    } else if (wv_ == 14) {
      // ---------- phase A: full columns, 8 alternating groups ----------
      float a0 = 0, a1 = 0, a2 = 0, a3 = 0;
      uint4 bA[8], bB[8];
      LOAD8(bA, 0) LOAD8(bB, 1)
      CONS8(bA, 0) LOAD8(bA, 2)
      CONS8(bB, 1) LOAD8(bB, 3)
      CONS8(bA, 2) LOAD8(bA, 4)
      CONS8(bB, 3) LOAD8(bB, 5)
      CONS8(bA, 4) LOAD8(bA, 6)
      CONS8(bB, 5) LOAD8(bB, 7)
      CONS8(bA, 6)
      CONS8(bB, 7)
      ph[0][mn] = (a0 + a1) + (a2 + a3);
    } else {
      // ---------- phase A: half-column, 4 alternating groups ----------
      if (tid < 512) {
        union { unsigned short u; _Float16 f; } c;
        c.u = Remb[(size_t)rowr * 512 + tid];
        rpre = (float)c.f;
      }
      float a0 = 0, a1 = 0, a2 = 0, a3 = 0;
      uint4 bA[8], bB[8];
      LOAD8(bA, 0) LOAD8(bB, 1)
      CONS8(bA, 0) LOAD8(bA, 2)
      CONS8(bB, 1) LOAD8(bB, 3)
      CONS8(bA, 2)
      CONS8(bB, 3)
      ph[mh0][mn] = (a0 + a1) + (a2 + a3);
    }
    __syncthreads();

    // ---------- phase B: ctx (LDS) + combine ----------
    if (tid < 512) {
      int n = tid;
      float c0 = 0, c1 = 0, c2 = 0, c3 = 0;
      #pragma unroll
      for (int g = 0; g < 16; ++g) {
        uint4 ev = el[g][n];
        uint4 wv = ((const uint4*)wpairS)[g];
        c0 = fdot2(ev.x, wv.x, c0); c1 = fdot2(ev.y, wv.y, c1);
        c2 = fdot2(ev.z, wv.z, c2); c3 = fdot2(ev.w, wv.w, c3);
      }
      float v = rpre + ph[0][n] + ph[1][n] + (c0 + c1) + (c2 + c3);
      float aa = eluf(v);
      X[(size_t)rowr * KX + 256 + n] = f2bf(aa);
      float bb = __shfl_down(aa, 1);
      if (!(n & 1)) hpair[n >> 1] = pkh2(aa, bb);
    }
    __syncthreads();
  }
}

// ---------- k_gemm: out = elu(X @ WoT^T + b_out), M=8192 N=8000 K=1280 ----------
// linear grid 4032 = 63x64, bijective XCD swizzle (4032 % 8 == 0)
__global__ __launch_bounds__(256) void k_gemm(
    const unsigned short* __restrict__ Xb,
    const unsigned short* __restrict__ WoT,
    const float* __restrict__ bout,
    float* __restrict__ out)
{
  __shared__ __align__(16) unsigned short As[BM * BK];
  __shared__ __align__(16) unsigned short Bs[BN * BK];
  int bid = blockIdx.x;
  int swz = (bid & 7) * 504 + (bid >> 3);
  int bx = swz % 63;
  int by = swz / 63;
  int tid = threadIdx.x;
  int wid = tid >> 6, lane = tid & 63;
  int wr = wid >> 1, wc = wid & 1;

  f32x4 acc[4][4];
  for (int i = 0; i < 4; ++i)
    for (int j = 0; j < 4; ++j) acc[i][j] = (f32x4)0.f;

  const unsigned short* Abase = Xb + (size_t)by * BM * KX;
  const unsigned short* Bbase = WoT + (size_t)bx * BN * KX;

  for (int kt = 0; kt < KX / BK; ++kt) {
    for (int j = 0; j < 4; ++j) {
      int c = tid + j * 256;
      int r = c >> 3, c16 = c & 7;
      int sk = c16 ^ (r & 7);
      gload16(Abase + (size_t)r * KX + kt * BK + sk * 8, (char*)As + c * 16);
      gload16(Bbase + (size_t)r * KX + kt * BK + sk * 8, (char*)Bs + c * 16);
    }
    __syncthreads();
    for (int ks = 0; ks < 2; ++ks) {
      short8 af[4], bf[4];
      int kc = ks * 4 + (lane >> 4);
      for (int i = 0; i < 4; ++i) {
        int r = wr * 64 + i * 16 + (lane & 15);
        af[i] = *(const short8*)((const char*)As + r * 128 + ((kc ^ (r & 7)) * 16));
      }
      for (int j = 0; j < 4; ++j) {
        int r = wc * 64 + j * 16 + (lane & 15);
        bf[j] = *(const short8*)((const char*)Bs + r * 128 + ((kc ^ (r & 7)) * 16));
      }
      for (int i = 0; i < 4; ++i)
        for (int j = 0; j < 4; ++j)
          acc[i][j] = __builtin_amdgcn_mfma_f32_16x16x32_bf16(af[i], bf[j], acc[i][j], 0, 0, 0);
    }
    __syncthreads();
  }

  int rl = lane >> 4, cl = lane & 15;
  for (int j = 0; j < 4; ++j) {
    int gn = bx * BN + wc * 64 + j * 16 + cl;
    if (gn >= VOC) continue;
    float bv = bout[gn];
    for (int i = 0; i < 4; ++i) {
      for (int q = 0; q < 4; ++q) {
        int gm = by * BM + wr * 64 + i * 16 + rl * 4 + q;
        int tt = gm >> 6, bb = gm & 63;
        float v = acc[i][j][q] + bv;
        v = v > 0.f ? v : (expf(v) - 1.f);
        out[((size_t)bb * TLEN + tt) * VOC + gn] = v;
      }
    }
  }
}

// ---------- launch ----------
extern "C" void kernel_launch(void* const* d_in, const int* in_sizes, int n_in,
                              void* d_out, int out_size, void* d_ws, size_t ws_size,
                              hipStream_t stream) {
  const float* enc  = (const float*)d_in[0];
  const int*   ro   = (const int*)d_in[1];
  const float* We1  = (const float*)d_in[2];
  const float* be1  = (const float*)d_in[3];
  const float* We2  = (const float*)d_in[4];
  const float* be2  = (const float*)d_in[5];
  const float* emb  = (const float*)d_in[6];
  const float* Wr   = (const float*)d_in[7];
  const float* brnn = (const float*)d_in[8];
  const float* Wo   = (const float*)d_in[9];
  const float* bo   = (const float*)d_in[10];

  char* ws = (char*)d_ws;
  unsigned short* X     = (unsigned short*)(ws);                 // 20,971,520
  unsigned short* WoT   = (unsigned short*)(ws + 20971520);      // 20,643,840
  unsigned short* W2    = (unsigned short*)(ws + 41615360);      //    524,288
  unsigned short* WembT = (unsigned short*)(ws + 42139648);      //    262,144
  unsigned short* WctxT = (unsigned short*)(ws + 42401792);      //    524,288
  unsigned short* ench  = (unsigned short*)(ws + 42926080);      //  8,388,608  (reused: encTh)
  float*          E1    = (float*)(ws + 51314688);               //    655,360
  unsigned short* Remb  = (unsigned short*)(ws + 51970048);      //  8,388,608  (reused: wh)
  unsigned short* encW2 = (unsigned short*)(ws + 60358656);      //  8,388,608
  unsigned short* encTh = ench;
  unsigned short* wh    = Remb;

  float* outs = (float*)d_out;
  float* wout = (float*)d_out + (size_t)BATCH * TLEN * VOC;

  // parallel precompute
  k_lc     <<<dim3(8192),     256, 0, stream>>>(ro, emb, X);
  k_e1     <<<dim3(2048),     256, 0, stream>>>(enc, We1, E1);
  k_tr_wout<<<dim3(126, 20),  256, 0, stream>>>(Wo, WoT);
  k_tr_w   <<<dim3(8, 4),     256, 0, stream>>>(Wr, WembT, 0, 256, 1);
  k_tr_w   <<<dim3(8, 8),     256, 0, stream>>>(Wr, WctxT, 768, 512, 0);
  k_prep_wr<<<dim3(1024),     256, 0, stream>>>(Wr, W2);
  k_ench   <<<dim3(4096),     256, 0, stream>>>(enc, ench);
  k_gs<0>  <<<dim3(4, 64),    256, 0, stream>>>(X, WembT, brnn, Remb);
  k_gs<1>  <<<dim3(4, 64),    256, 0, stream>>>(ench, WctxT, brnn, encW2);
  // sequential core
  k_recur  <<<dim3(64),      1024, 0, stream>>>(We1, be1, We2, be2,
                                                (const uint4*)W2, (const uint4*)encW2,
                                                Remb, E1, X, wout);
  // post: ctx fill + big GEMM
  k_wh     <<<dim3(1024),     256, 0, stream>>>(wout, wh);
  k_tr_encb<<<dim3(64, 8, 2), 256, 0, stream>>>(enc, encTh);
  k_gs<2>  <<<dim3(4, 64),    256, 0, stream>>>(wh, encTh, brnn, X);
  k_gemm   <<<dim3(4032),     256, 0, stream>>>(X, WoT, bo, outs);
  (void)in_sizes; (void)n_in; (void)out_size; (void)ws_size;
}

// Round 10
// 1307.427 us; speedup vs baseline: 2.0232x; 1.6540x over previous
//
#include <hip/hip_runtime.h>
#include <hip/hip_bf16.h>
#include <stdint.h>

#define BATCH 64
#define SLEN 128
#define TLEN 128
#define ENCD 512
#define DECD 512
#define EMBD 256
#define VOC  8000
#define HE   20
#define KX   1280      // EMB + DEC + ENC
#define NPAD 8064      // VOC padded to 63*128

typedef __attribute__((ext_vector_type(8))) short short8;
typedef __attribute__((ext_vector_type(8))) _Float16 half8v;
typedef __attribute__((ext_vector_type(4))) float f32x4;
typedef _Float16 h2 __attribute__((ext_vector_type(2)));

// ---------- helpers ----------
__device__ inline unsigned short f2bf(float f) {
  union { float f; uint32_t u; } v; v.f = f;
  uint32_t r = v.u + 0x7fff + ((v.u >> 16) & 1);
  return (unsigned short)(r >> 16);
}
__device__ inline unsigned short f16bits(float f) {
  union { _Float16 h; unsigned short u; } c; c.h = (_Float16)f; return c.u;
}
__device__ inline uint32_t pkh2(float a, float b) {
  union { h2 h; uint32_t u; } v;
  v.h = h2{(_Float16)a, (_Float16)b};
  return v.u;
}
__device__ inline float fdot2(uint32_t a, uint32_t b, float c) {
#if __has_builtin(__builtin_amdgcn_fdot2)
  union { uint32_t u; h2 h; } x, y; x.u = a; y.u = b;
  return __builtin_amdgcn_fdot2(x.h, y.h, c, false);
#else
  union { uint32_t u; h2 h; } x, y; x.u = a; y.u = b;
  return c + (float)x.h[0] * (float)y.h[0] + (float)x.h[1] * (float)y.h[1];
#endif
}
__device__ inline float eluf(float x) { return x > 0.f ? x : (expf(x) - 1.f); }

typedef const __attribute__((address_space(1))) unsigned int* gptr_t;
typedef __attribute__((address_space(3))) unsigned int* lptr_t;
__device__ inline void gload16(const void* g, void* l) {
  __builtin_amdgcn_global_load_lds((gptr_t)g, (lptr_t)l, 16, 0, 0);
}

// ---------- k_e1: E1t[b][h][s] = enc[b,s,:] @ We1[0:512,h] (transposed store) ----------
__global__ __launch_bounds__(256) void k_e1(const float* __restrict__ enc,
                                            const float* __restrict__ We1,
                                            float* __restrict__ E1) {
  __shared__ float rowbuf[4][ENCD];
  __shared__ float part[4][HE][2];
  int r0 = blockIdx.x * 4;
  int tid = threadIdx.x;
  for (int i = tid; i < 4 * ENCD; i += 256) {
    int rl = i >> 9, e = i & 511;
    rowbuf[rl][e] = enc[(size_t)(r0 + rl) * ENCD + e];
  }
  __syncthreads();
  if (tid < 160) {
    int kg = tid / 80, rem = tid % 80, rl = rem / 20, h = rem % 20;
    float acc = 0.f;
    for (int k = kg * 256; k < kg * 256 + 256; ++k)
      acc += rowbuf[rl][k] * We1[k * HE + h];
    part[rl][h][kg] = acc;
  }
  __syncthreads();
  if (tid < 80) {
    int rl = tid / 20, h = tid % 20;
    int r = r0 + rl, bb = r >> 7, ss = r & 127;
    E1[((size_t)bb * HE + h) * SLEN + ss] = part[rl][h][0] + part[rl][h][1];
  }
}

// ---------- k_tr_wout: W_out [1280][8000] f32 -> WoT [8064][1280] bf16 ----------
__global__ __launch_bounds__(256) void k_tr_wout(const float* __restrict__ Wo,
                                                 unsigned short* __restrict__ WoT) {
  __shared__ float tile[64][65];
  int n0 = blockIdx.x * 64, k0 = blockIdx.y * 64;
  int tid = threadIdx.x;
  for (int i = tid; i < 4096; i += 256) {
    int kk = i >> 6, nn = i & 63;
    int n = n0 + nn;
    tile[kk][nn] = (n < VOC) ? Wo[(size_t)(k0 + kk) * VOC + n] : 0.f;
  }
  __syncthreads();
  for (int i = tid; i < 4096; i += 256) {
    int nn = i >> 6, kk = i & 63;
    WoT[(size_t)(n0 + nn) * KX + k0 + kk] = f2bf(tile[kk][nn]);
  }
}

// ---------- k_tr_w: src rows [k0 .. k0+KN) of [*][512] f32 -> dst [512][KN] ----------
__global__ __launch_bounds__(256) void k_tr_w(const float* __restrict__ src,
                                              unsigned short* __restrict__ dst,
                                              int k0, int KN, int fmt) {
  __shared__ float tile[64][65];
  int n0 = blockIdx.x * 64, kt = blockIdx.y * 64;
  int tid = threadIdx.x;
  for (int i = tid; i < 4096; i += 256) {
    int kk = i >> 6, nn = i & 63;
    tile[kk][nn] = src[(size_t)(k0 + kt + kk) * 512 + n0 + nn];
  }
  __syncthreads();
  for (int i = tid; i < 4096; i += 256) {
    int nn = i >> 6, kk = i & 63;
    float v = tile[kk][nn];
    dst[(size_t)(n0 + nn) * KN + kt + kk] = fmt ? f2bf(v) : f16bits(v);
  }
}

// ---------- k_prep_wr: Wr rows 256..768 -> chunked f16 W2[(h*32+kc)*512+n][8] ----------
__global__ __launch_bounds__(256) void k_prep_wr(const float* __restrict__ Wr,
                                                 unsigned short* __restrict__ W2) {
  int i = blockIdx.x * 256 + threadIdx.x;
  int n = i & 511;
  int j = (i >> 9) & 7;
  int kc = (i >> 12) & 31;
  int h = (i >> 17) & 1;
  int k = h * 256 + kc * 8 + j;
  W2[(((size_t)(h * 32 + kc) * 512) + n) * 8 + j] = f16bits(Wr[(size_t)(256 + k) * 512 + n]);
}

// ---------- k_ench: enc f32 -> f16 flat [8192][512] ----------
__global__ __launch_bounds__(256) void k_ench(const float* __restrict__ enc,
                                              unsigned short* __restrict__ ench) {
  int i = (blockIdx.x * 256 + threadIdx.x) * 4;
  float4 v = *(const float4*)(enc + i);
  ushort4 o = { f16bits(v.x), f16bits(v.y), f16bits(v.z), f16bits(v.w) };
  *(ushort4*)(ench + i) = o;
}

// ---------- k_wh: wout f32 [8192][128] -> f16 ----------
__global__ __launch_bounds__(256) void k_wh(const float* __restrict__ wout,
                                            unsigned short* __restrict__ wh) {
  int i = (blockIdx.x * 256 + threadIdx.x) * 4;
  float4 v = *(const float4*)(wout + i);
  ushort4 o = { f16bits(v.x), f16bits(v.y), f16bits(v.z), f16bits(v.w) };
  *(ushort4*)(wh + i) = o;
}

// ---------- k_tr_encb: enc [b][s][e] f32 -> encTh [b][e][s] f16 ----------
__global__ __launch_bounds__(256) void k_tr_encb(const float* __restrict__ enc,
                                                 unsigned short* __restrict__ encT) {
  __shared__ float tile[64][65];
  int b = blockIdx.x, e0 = blockIdx.y * 64, s0 = blockIdx.z * 64;
  int tid = threadIdx.x;
  const float* eb = enc + (size_t)b * SLEN * ENCD;
  for (int i = tid; i < 4096; i += 256) {
    int ss = i >> 6, ee = i & 63;
    tile[ss][ee] = eb[(size_t)(s0 + ss) * ENCD + e0 + ee];
  }
  __syncthreads();
  unsigned short* ob = encT + (size_t)b * ENCD * SLEN;
  for (int i = tid; i < 4096; i += 256) {
    int ee = i >> 6, ss = i & 63;
    ob[(size_t)(e0 + ee) * SLEN + s0 + ss] = f16bits(tile[ss][ee]);
  }
}

// ---------- k_lc: X[t*B+b][0:256] = bf16(emb[lc]) ----------
__global__ __launch_bounds__(256) void k_lc(const int* __restrict__ ro,
                                            const float* __restrict__ emb,
                                            unsigned short* __restrict__ X) {
  int r = blockIdx.x;
  int t = r >> 6, b = r & 63;
  int lc = (t == 0) ? 0 : ro[b * TLEN + t - 1];
  lc = ((lc % VOC) + VOC) % VOC;
  X[(size_t)r * KX + threadIdx.x] = f2bf(emb[(size_t)lc * EMBD + threadIdx.x]);
}

// ---------- k_gs<MODE>: 128x128xK MFMA GEMM ----------
#define BM 128
#define BN 128
#define BK 64

template<int MODE>
__global__ __launch_bounds__(256) void k_gs(
    const unsigned short* __restrict__ A,
    const unsigned short* __restrict__ B,
    const float* __restrict__ bias,
    unsigned short* __restrict__ Cout)
{
  constexpr int As = (MODE == 0) ? KX : (MODE == 1 ? 512 : 128);
  constexpr int Bs = (MODE == 0) ? 256 : (MODE == 1 ? 512 : 128);
  constexpr int KT = (MODE == 0) ? 4 : (MODE == 1 ? 8 : 2);
  __shared__ __align__(16) unsigned short Asd[BM * BK];
  __shared__ __align__(16) unsigned short Bsd[BN * BK];
  int bx = blockIdx.x, by = blockIdx.y;
  int tid = threadIdx.x;
  int wid = tid >> 6, lane = tid & 63;
  int wr = wid >> 1, wc = wid & 1;

  f32x4 acc[4][4];
  for (int i = 0; i < 4; ++i)
    for (int j = 0; j < 4; ++j) acc[i][j] = (f32x4)0.f;

  const unsigned short* Abase = A + (size_t)by * BM * As;
  const unsigned short* Bbase = B + (size_t)bx * BN * Bs + (MODE == 2 ? (size_t)by * 512 * 128 : 0);

  for (int kt = 0; kt < KT; ++kt) {
    for (int j = 0; j < 4; ++j) {
      int c = tid + j * 256;
      int r = c >> 3, c16 = c & 7;
      int sk = c16 ^ (r & 7);
      gload16(Abase + (size_t)r * As + kt * BK + sk * 8, (char*)Asd + c * 16);
      gload16(Bbase + (size_t)r * Bs + kt * BK + sk * 8, (char*)Bsd + c * 16);
    }
    __syncthreads();
    for (int ks = 0; ks < 2; ++ks) {
      short8 af[4], bf[4];
      int kc = ks * 4 + (lane >> 4);
      for (int i = 0; i < 4; ++i) {
        int r = wr * 64 + i * 16 + (lane & 15);
        af[i] = *(const short8*)((const char*)Asd + r * 128 + ((kc ^ (r & 7)) * 16));
      }
      for (int j = 0; j < 4; ++j) {
        int r = wc * 64 + j * 16 + (lane & 15);
        bf[j] = *(const short8*)((const char*)Bsd + r * 128 + ((kc ^ (r & 7)) * 16));
      }
      for (int i = 0; i < 4; ++i)
        for (int j = 0; j < 4; ++j) {
          if constexpr (MODE == 0)
            acc[i][j] = __builtin_amdgcn_mfma_f32_16x16x32_bf16(af[i], bf[j], acc[i][j], 0, 0, 0);
          else
            acc[i][j] = __builtin_amdgcn_mfma_f32_16x16x32_f16(
                __builtin_bit_cast(half8v, af[i]), __builtin_bit_cast(half8v, bf[j]), acc[i][j], 0, 0, 0);
        }
    }
    __syncthreads();
  }

  int rl = lane >> 4, cl = lane & 15;
  for (int j = 0; j < 4; ++j) {
    int gn = bx * BN + wc * 64 + j * 16 + cl;
    for (int i = 0; i < 4; ++i) {
      for (int q = 0; q < 4; ++q) {
        int gm = by * BM + wr * 64 + i * 16 + rl * 4 + q;
        float v = acc[i][j][q];
        if constexpr (MODE == 0) {
          Cout[(size_t)gm * 512 + gn] = f16bits(v + bias[gn]);
        } else if constexpr (MODE == 1) {
          int bb = gm >> 7, s = gm & 127;
          Cout[(((size_t)(bb * 16 + (s >> 3)) * 512) + gn) * 8 + (s & 7)] = f16bits(v);
        } else {
          int tt = gm & 127, bb = gm >> 7;
          Cout[((size_t)tt * 64 + bb) * KX + 768 + gn] = f2bf(v);
        }
      }
    }
  }
}

// ---------- k_recur: r7 loop text on every path; balanced map ----------
// waves 0..13: half-columns (4 groups), as round 7.
// wave 14:     mh=0 half of cols 448..511 (4 groups, was 8).
// wave 15:     attention chain (raised prio), THEN mh=1 half of cols 448..511
//              (4 groups, identical loop text; attention regs dead by then).
#define STREAM4(PH) { \
  float a0 = 0, a1 = 0, a2 = 0, a3 = 0; \
  uint4 cb[8], nb[8]; \
  _Pragma("unroll") \
  for (int j = 0; j < 8; ++j) cb[j] = Wp[(size_t)j * 512]; \
  for (int blk = 0; blk < 4; ++blk) { \
    if (blk + 1 < 4) { \
      _Pragma("unroll") \
      for (int j = 0; j < 8; ++j) nb[j] = Wp[(size_t)((blk + 1) * 8 + j) * 512]; \
    } \
    _Pragma("unroll") \
    for (int j = 0; j < 8; ++j) { \
      uint4 wv = cb[j]; uint4 xv = hp4[hbase + blk * 8 + j]; \
      a0 = fdot2(wv.x, xv.x, a0); a1 = fdot2(wv.y, xv.y, a1); \
      a2 = fdot2(wv.z, xv.z, a2); a3 = fdot2(wv.w, xv.w, a3); \
    } \
    _Pragma("unroll") \
    for (int j = 0; j < 8; ++j) cb[j] = nb[j]; \
  } \
  ph[PH][mn] = (a0 + a1) + (a2 + a3); }

__global__ __launch_bounds__(1024) void k_recur(
    const float* __restrict__ We1,     // [1024][20]
    const float* __restrict__ be1,
    const float* __restrict__ We2,
    const float* __restrict__ be2,
    const uint4* __restrict__ W2,      // chunked f16, 32768 uint4
    const uint4* __restrict__ encW2,   // [64][16][512] uint4
    const unsigned short* __restrict__ Remb, // f16 [8192][512] (brnn folded)
    const float* __restrict__ E1g,     // [64][20][128]
    unsigned short* __restrict__ X,    // [8192][1280] bf16
    float* __restrict__ wout)          // [64][128][128]
{
  __shared__ __align__(16) uint4 el[16][512];   // 128 KB: encW2 slice (static)
  __shared__ uint32_t E1p[HE][SLEN / 2];        // 5 KB (f16 pairs)
  __shared__ uint32_t w1p[HE][257];             // 20.6 KB
  __shared__ uint32_t hpair[DECD / 2];          // 1 KB
  __shared__ uint32_t wpairS[SLEN / 2];         // 256 B
  __shared__ float ph[2][DECD];                 // 4 KB
  __shared__ float be1s[HE], w2s[HE];
  __shared__ float be2s;

  int b = blockIdx.x, tid = threadIdx.x;

  for (int i = tid; i < 16 * 512; i += 1024) ((uint4*)el)[i] = encW2[(size_t)b * 8192 + i];
  for (int i = tid; i < HE * (SLEN / 2); i += 1024) {
    int h = i >> 6, p = i & 63;
    const float* ebase = E1g + ((size_t)b * HE + h) * SLEN;
    ((uint32_t*)E1p)[i] = pkh2(ebase[2 * p], ebase[2 * p + 1]);
  }
  for (int i = tid; i < HE * 256; i += 1024) {
    int h = i >> 8, p = i & 255;
    w1p[h][p] = pkh2(We1[(size_t)(ENCD + 2 * p) * HE + h],
                     We1[(size_t)(ENCD + 2 * p + 1) * HE + h]);
  }
  for (int i = tid; i < DECD / 2; i += 1024) hpair[i] = 0;
  for (int i = tid; i < DECD; i += 1024) { ph[0][i] = 0.f; ph[1][i] = 0.f; }
  if (tid < HE) { be1s[tid] = be1[tid]; w2s[tid] = We2[tid]; }
  if (tid == 0) be2s = be2[0];
  __syncthreads();

  const int lane = tid & 63;
  const int wv_ = tid >> 6;
  int mn, mh0;
  if (tid < 448)      { mn = tid;        mh0 = 0; }
  else if (tid < 896) { mn = tid - 448;  mh0 = 1; }
  else if (tid < 960) { mn = 448 + lane; mh0 = 0; }   // wave 14
  else                { mn = 448 + lane; mh0 = 1; }   // wave 15 (after attn)
  const uint4* Wp = W2 + (size_t)(mh0 * 32) * 512 + mn;
  const uint4* hp4 = (const uint4*)hpair;
  const int hbase = mh0 * 32;

  // attention lane roles (wave 15)
  int ah = lane % 20, aseg = lane / 20;
  int q0 = aseg * 86;
  int q1 = (aseg == 2) ? 256 : q0 + 86;
  if (aseg >= 3) { q0 = 0; q1 = 0; }

  for (int t = 0; t < TLEN; ++t) {
    const int rowr = t * BATCH + b;
    float rpre = 0.f;

    if (wv_ < 15) {
      // ---------- phase A: stream (4 groups, r7 loop text) ----------
      if (tid < 512) {
        union { unsigned short u; _Float16 f; } c;
        c.u = Remb[(size_t)rowr * 512 + tid];
        rpre = (float)c.f;
      }
      STREAM4(mh0)
    } else {
      // ---------- phase A: attention chain, raised priority ----------
      __builtin_amdgcn_s_setprio(1);
      float p0 = 0, p1 = 0;
      for (int q = q0; q < q1; q += 2) {
        p0 = fdot2(w1p[ah][q], hpair[q], p0);
        p1 = fdot2(w1p[ah][q + 1], hpair[q + 1], p1);
      }
      float p = p0 + p1;
      float pa = __shfl(p, lane + 20);
      float pb = __shfl(p, lane + 40);
      float edv = p + pa + pb + ((lane < HE) ? be1s[lane] : 0.f);
      float e0a = 0.f, e1a = 0.f;
      #pragma unroll
      for (int h = 0; h < HE; ++h) {
        union { uint32_t u; h2 hh; } e; e.u = E1p[h][lane];
        float ed = __shfl(edv, h);
        e0a += eluf((float)e.hh[0] + ed) * w2s[h];
        e1a += eluf((float)e.hh[1] + ed) * w2s[h];
      }
      float s0 = expf(eluf(e0a + be2s));
      float s1 = expf(eluf(e1a + be2s));
      float tot = s0 + s1;
      #pragma unroll
      for (int o = 1; o < 64; o <<= 1) tot += __shfl_xor(tot, o);
      float inv = 1.f / tot;
      float w0 = s0 * inv, w1 = s1 * inv;
      wpairS[lane] = pkh2(w0, w1);
      float2 wv2 = { w0, w1 };
      *(float2*)(wout + ((size_t)b * TLEN + t) * SLEN + 2 * lane) = wv2;
      __builtin_amdgcn_s_setprio(0);
      // ---------- then its share of the stream (4 groups, same loop text) ----------
      STREAM4(1)
    }
    __syncthreads();

    // ---------- phase B: ctx (LDS) + combine ----------
    if (tid < 512) {
      int n = tid;
      float c0 = 0, c1 = 0, c2 = 0, c3 = 0;
      #pragma unroll
      for (int g = 0; g < 16; ++g) {
        uint4 ev = el[g][n];
        uint4 wv = ((const uint4*)wpairS)[g];
        c0 = fdot2(ev.x, wv.x, c0); c1 = fdot2(ev.y, wv.y, c1);
        c2 = fdot2(ev.z, wv.z, c2); c3 = fdot2(ev.w, wv.w, c3);
      }
      float v = rpre + ph[0][n] + ph[1][n] + (c0 + c1) + (c2 + c3);
      float aa = eluf(v);
      X[(size_t)rowr * KX + 256 + n] = f2bf(aa);
      float bb = __shfl_down(aa, 1);
      if (!(n & 1)) hpair[n >> 1] = pkh2(aa, bb);
    }
    __syncthreads();
  }
}

// ---------- k_gemm: out = elu(X @ WoT^T + b_out), M=8192 N=8000 K=1280 ----------
// linear grid 4032 = 63x64, bijective XCD swizzle (4032 % 8 == 0)
__global__ __launch_bounds__(256) void k_gemm(
    const unsigned short* __restrict__ Xb,
    const unsigned short* __restrict__ WoT,
    const float* __restrict__ bout,
    float* __restrict__ out)
{
  __shared__ __align__(16) unsigned short As[BM * BK];
  __shared__ __align__(16) unsigned short Bs[BN * BK];
  int bid = blockIdx.x;
  int swz = (bid & 7) * 504 + (bid >> 3);
  int bx = swz % 63;
  int by = swz / 63;
  int tid = threadIdx.x;
  int wid = tid >> 6, lane = tid & 63;
  int wr = wid >> 1, wc = wid & 1;

  f32x4 acc[4][4];
  for (int i = 0; i < 4; ++i)
    for (int j = 0; j < 4; ++j) acc[i][j] = (f32x4)0.f;

  const unsigned short* Abase = Xb + (size_t)by * BM * KX;
  const unsigned short* Bbase = WoT + (size_t)bx * BN * KX;

  for (int kt = 0; kt < KX / BK; ++kt) {
    for (int j = 0; j < 4; ++j) {
      int c = tid + j * 256;
      int r = c >> 3, c16 = c & 7;
      int sk = c16 ^ (r & 7);
      gload16(Abase + (size_t)r * KX + kt * BK + sk * 8, (char*)As + c * 16);
      gload16(Bbase + (size_t)r * KX + kt * BK + sk * 8, (char*)Bs + c * 16);
    }
    __syncthreads();
    for (int ks = 0; ks < 2; ++ks) {
      short8 af[4], bf[4];
      int kc = ks * 4 + (lane >> 4);
      for (int i = 0; i < 4; ++i) {
        int r = wr * 64 + i * 16 + (lane & 15);
        af[i] = *(const short8*)((const char*)As + r * 128 + ((kc ^ (r & 7)) * 16));
      }
      for (int j = 0; j < 4; ++j) {
        int r = wc * 64 + j * 16 + (lane & 15);
        bf[j] = *(const short8*)((const char*)Bs + r * 128 + ((kc ^ (r & 7)) * 16));
      }
      for (int i = 0; i < 4; ++i)
        for (int j = 0; j < 4; ++j)
          acc[i][j] = __builtin_amdgcn_mfma_f32_16x16x32_bf16(af[i], bf[j], acc[i][j], 0, 0, 0);
    }
    __syncthreads();
  }

  int rl = lane >> 4, cl = lane & 15;
  for (int j = 0; j < 4; ++j) {
    int gn = bx * BN + wc * 64 + j * 16 + cl;
    if (gn >= VOC) continue;
    float bv = bout[gn];
    for (int i = 0; i < 4; ++i) {
      for (int q = 0; q < 4; ++q) {
        int gm = by * BM + wr * 64 + i * 16 + rl * 4 + q;
        int tt = gm >> 6, bb = gm & 63;
        float v = acc[i][j][q] + bv;
        v = v > 0.f ? v : (expf(v) - 1.f);
        out[((size_t)bb * TLEN + tt) * VOC + gn] = v;
      }
    }
  }
}

// ---------- launch ----------
extern "C" void kernel_launch(void* const* d_in, const int* in_sizes, int n_in,
                              void* d_out, int out_size, void* d_ws, size_t ws_size,
                              hipStream_t stream) {
  const float* enc  = (const float*)d_in[0];
  const int*   ro   = (const int*)d_in[1];
  const float* We1  = (const float*)d_in[2];
  const float* be1  = (const float*)d_in[3];
  const float* We2  = (const float*)d_in[4];
  const float* be2  = (const float*)d_in[5];
  const float* emb  = (const float*)d_in[6];
  const float* Wr   = (const float*)d_in[7];
  const float* brnn = (const float*)d_in[8];
  const float* Wo   = (const float*)d_in[9];
  const float* bo   = (const float*)d_in[10];

  char* ws = (char*)d_ws;
  unsigned short* X     = (unsigned short*)(ws);                 // 20,971,520
  unsigned short* WoT   = (unsigned short*)(ws + 20971520);      // 20,643,840
  unsigned short* W2    = (unsigned short*)(ws + 41615360);      //    524,288
  unsigned short* WembT = (unsigned short*)(ws + 42139648);      //    262,144
  unsigned short* WctxT = (unsigned short*)(ws + 42401792);      //    524,288
  unsigned short* ench  = (unsigned short*)(ws + 42926080);      //  8,388,608  (reused: encTh)
  float*          E1    = (float*)(ws + 51314688);               //    655,360
  unsigned short* Remb  = (unsigned short*)(ws + 51970048);      //  8,388,608  (reused: wh)
  unsigned short* encW2 = (unsigned short*)(ws + 60358656);      //  8,388,608
  unsigned short* encTh = ench;
  unsigned short* wh    = Remb;

  float* outs = (float*)d_out;
  float* wout = (float*)d_out + (size_t)BATCH * TLEN * VOC;

  // parallel precompute
  k_lc     <<<dim3(8192),     256, 0, stream>>>(ro, emb, X);
  k_e1     <<<dim3(2048),     256, 0, stream>>>(enc, We1, E1);
  k_tr_wout<<<dim3(126, 20),  256, 0, stream>>>(Wo, WoT);
  k_tr_w   <<<dim3(8, 4),     256, 0, stream>>>(Wr, WembT, 0, 256, 1);
  k_tr_w   <<<dim3(8, 8),     256, 0, stream>>>(Wr, WctxT, 768, 512, 0);
  k_prep_wr<<<dim3(1024),     256, 0, stream>>>(Wr, W2);
  k_ench   <<<dim3(4096),     256, 0, stream>>>(enc, ench);
  k_gs<0>  <<<dim3(4, 64),    256, 0, stream>>>(X, WembT, brnn, Remb);
  k_gs<1>  <<<dim3(4, 64),    256, 0, stream>>>(ench, WctxT, brnn, encW2);
  // sequential core
  k_recur  <<<dim3(64),      1024, 0, stream>>>(We1, be1, We2, be2,
                                                (const uint4*)W2, (const uint4*)encW2,
                                                Remb, E1, X, wout);
  // post: ctx fill + big GEMM
  k_wh     <<<dim3(1024),     256, 0, stream>>>(wout, wh);
  k_tr_encb<<<dim3(64, 8, 2), 256, 0, stream>>>(enc, encTh);
  k_gs<2>  <<<dim3(4, 64),    256, 0, stream>>>(wh, encTh, brnn, X);
  k_gemm   <<<dim3(4032),     256, 0, stream>>>(X, WoT, bo, outs);
  (void)in_sizes; (void)n_in; (void)out_size; (void)ws_size;
}

// Round 11
// 1255.968 us; speedup vs baseline: 2.1061x; 1.0410x over previous
//
#include <hip/hip_runtime.h>
#include <hip/hip_bf16.h>
#include <stdint.h>

#define BATCH 64
#define SLEN 128
#define TLEN 128
#define ENCD 512
#define DECD 512
#define EMBD 256
#define VOC  8000
#define HE   20
#define KX   1280      // EMB + DEC + ENC
#define NPAD 8064      // VOC padded to 63*128

typedef __attribute__((ext_vector_type(8))) short short8;
typedef __attribute__((ext_vector_type(8))) _Float16 half8v;
typedef __attribute__((ext_vector_type(4))) float f32x4;
typedef _Float16 h2 __attribute__((ext_vector_type(2)));

// ---------- helpers ----------
__device__ inline unsigned short f2bf(float f) {
  union { float f; uint32_t u; } v; v.f = f;
  uint32_t r = v.u + 0x7fff + ((v.u >> 16) & 1);
  return (unsigned short)(r >> 16);
}
__device__ inline unsigned short f16bits(float f) {
  union { _Float16 h; unsigned short u; } c; c.h = (_Float16)f; return c.u;
}
__device__ inline uint32_t pkh2(float a, float b) {
  union { h2 h; uint32_t u; } v;
  v.h = h2{(_Float16)a, (_Float16)b};
  return v.u;
}
__device__ inline float fdot2(uint32_t a, uint32_t b, float c) {
#if __has_builtin(__builtin_amdgcn_fdot2)
  union { uint32_t u; h2 h; } x, y; x.u = a; y.u = b;
  return __builtin_amdgcn_fdot2(x.h, y.h, c, false);
#else
  union { uint32_t u; h2 h; } x, y; x.u = a; y.u = b;
  return c + (float)x.h[0] * (float)y.h[0] + (float)x.h[1] * (float)y.h[1];
#endif
}
__device__ inline float eluf(float x) { return x > 0.f ? x : (expf(x) - 1.f); }

typedef const __attribute__((address_space(1))) unsigned int* gptr_t;
typedef __attribute__((address_space(3))) unsigned int* lptr_t;
__device__ inline void gload16(const void* g, void* l) {
  __builtin_amdgcn_global_load_lds((gptr_t)g, (lptr_t)l, 16, 0, 0);
}

// ---------- k_pre1: merged k_lc / k_ench / k_e1 ----------
// blocks 0..8191    : X[t*B+b][0:256] = bf16(emb[lc])
// blocks 8192..12287: enc f32 -> f16 flat
// blocks 12288..14335: E1t[b][h][s] = enc[b,s,:] @ We1[0:512,h]
__global__ __launch_bounds__(256) void k_pre1(const int* __restrict__ ro,
                                              const float* __restrict__ emb,
                                              unsigned short* __restrict__ X,
                                              const float* __restrict__ enc,
                                              unsigned short* __restrict__ ench,
                                              const float* __restrict__ We1,
                                              float* __restrict__ E1) {
  __shared__ float rowbuf[4][ENCD];
  __shared__ float part[4][HE][2];
  int bid = blockIdx.x, tid = threadIdx.x;
  if (bid < 8192) {
    int r = bid;
    int t = r >> 6, b = r & 63;
    int lc = (t == 0) ? 0 : ro[b * TLEN + t - 1];
    lc = ((lc % VOC) + VOC) % VOC;
    X[(size_t)r * KX + tid] = f2bf(emb[(size_t)lc * EMBD + tid]);
  } else if (bid < 12288) {
    int i = ((bid - 8192) * 256 + tid) * 4;
    float4 v = *(const float4*)(enc + i);
    ushort4 o = { f16bits(v.x), f16bits(v.y), f16bits(v.z), f16bits(v.w) };
    *(ushort4*)(ench + i) = o;
  } else {
    int r0 = (bid - 12288) * 4;
    for (int i = tid; i < 4 * ENCD; i += 256) {
      int rl = i >> 9, e = i & 511;
      rowbuf[rl][e] = enc[(size_t)(r0 + rl) * ENCD + e];
    }
    __syncthreads();
    if (tid < 160) {
      int kg = tid / 80, rem = tid % 80, rl = rem / 20, h = rem % 20;
      float acc = 0.f;
      for (int k = kg * 256; k < kg * 256 + 256; ++k)
        acc += rowbuf[rl][k] * We1[k * HE + h];
      part[rl][h][kg] = acc;
    }
    __syncthreads();
    if (tid < 80) {
      int rl = tid / 20, h = tid % 20;
      int r = r0 + rl, bb = r >> 7, ss = r & 127;
      E1[((size_t)bb * HE + h) * SLEN + ss] = part[rl][h][0] + part[rl][h][1];
    }
  }
}

// ---------- k_pre2: merged k_tr_w(WembT) / k_tr_w(WctxT) / k_prep_wr ----------
__global__ __launch_bounds__(256) void k_pre2(const float* __restrict__ Wr,
                                              unsigned short* __restrict__ WembT,
                                              unsigned short* __restrict__ WctxT,
                                              unsigned short* __restrict__ W2) {
  __shared__ float tile[64][65];
  int bid = blockIdx.x, tid = threadIdx.x;
  if (bid < 96) {
    // transpose branch: src rows [k0..k0+KN) of Wr[*][512] -> dst [512][KN]
    int k0, KN, fmt, bx, by;
    unsigned short* dst;
    if (bid < 32) { k0 = 0;   KN = 256; fmt = 1; bx = bid & 7; by = bid >> 3; dst = WembT; }
    else          { int id2 = bid - 32; k0 = 768; KN = 512; fmt = 0; bx = id2 & 7; by = id2 >> 3; dst = WctxT; }
    int n0 = bx * 64, kt = by * 64;
    for (int i = tid; i < 4096; i += 256) {
      int kk = i >> 6, nn = i & 63;
      tile[kk][nn] = Wr[(size_t)(k0 + kt + kk) * 512 + n0 + nn];
    }
    __syncthreads();
    for (int i = tid; i < 4096; i += 256) {
      int nn = i >> 6, kk = i & 63;
      float v = tile[kk][nn];
      dst[(size_t)(n0 + nn) * KN + kt + kk] = fmt ? f2bf(v) : f16bits(v);
    }
  } else {
    int i = (bid - 96) * 256 + tid;
    int n = i & 511;
    int j = (i >> 9) & 7;
    int kc = (i >> 12) & 31;
    int h = (i >> 17) & 1;
    int k = h * 256 + kc * 8 + j;
    W2[(((size_t)(h * 32 + kc) * 512) + n) * 8 + j] = f16bits(Wr[(size_t)(256 + k) * 512 + n]);
  }
}

// ---------- k_wh: wout f32 [8192][128] -> f16 ----------
__global__ __launch_bounds__(256) void k_wh(const float* __restrict__ wout,
                                            unsigned short* __restrict__ wh) {
  int i = (blockIdx.x * 256 + threadIdx.x) * 4;
  float4 v = *(const float4*)(wout + i);
  ushort4 o = { f16bits(v.x), f16bits(v.y), f16bits(v.z), f16bits(v.w) };
  *(ushort4*)(wh + i) = o;
}

// ---------- k_gs<MODE>: 128x128xK MFMA GEMM ----------
#define BM 128
#define BN 128
#define BK 64

template<int MODE>
__global__ __launch_bounds__(256) void k_gs(
    const unsigned short* __restrict__ A,
    const unsigned short* __restrict__ B,
    const float* __restrict__ bias,
    unsigned short* __restrict__ Cout)
{
  constexpr int As = (MODE == 0) ? KX : (MODE == 1 ? 512 : 128);
  constexpr int Bs = (MODE == 0) ? 256 : (MODE == 1 ? 512 : 128);
  constexpr int KT = (MODE == 0) ? 4 : (MODE == 1 ? 8 : 2);
  __shared__ __align__(16) unsigned short Asd[BM * BK];
  __shared__ __align__(16) unsigned short Bsd[BN * BK];
  int bx = blockIdx.x, by = blockIdx.y;
  int tid = threadIdx.x;
  int wid = tid >> 6, lane = tid & 63;
  int wr = wid >> 1, wc = wid & 1;

  f32x4 acc[4][4];
  for (int i = 0; i < 4; ++i)
    for (int j = 0; j < 4; ++j) acc[i][j] = (f32x4)0.f;

  const unsigned short* Abase = A + (size_t)by * BM * As;
  const unsigned short* Bbase = B + (size_t)bx * BN * Bs + (MODE == 2 ? (size_t)by * 512 * 128 : 0);

  for (int kt = 0; kt < KT; ++kt) {
    for (int j = 0; j < 4; ++j) {
      int c = tid + j * 256;
      int r = c >> 3, c16 = c & 7;
      int sk = c16 ^ (r & 7);
      gload16(Abase + (size_t)r * As + kt * BK + sk * 8, (char*)Asd + c * 16);
      gload16(Bbase + (size_t)r * Bs + kt * BK + sk * 8, (char*)Bsd + c * 16);
    }
    __syncthreads();
    for (int ks = 0; ks < 2; ++ks) {
      short8 af[4], bf[4];
      int kc = ks * 4 + (lane >> 4);
      for (int i = 0; i < 4; ++i) {
        int r = wr * 64 + i * 16 + (lane & 15);
        af[i] = *(const short8*)((const char*)Asd + r * 128 + ((kc ^ (r & 7)) * 16));
      }
      for (int j = 0; j < 4; ++j) {
        int r = wc * 64 + j * 16 + (lane & 15);
        bf[j] = *(const short8*)((const char*)Bsd + r * 128 + ((kc ^ (r & 7)) * 16));
      }
      for (int i = 0; i < 4; ++i)
        for (int j = 0; j < 4; ++j) {
          if constexpr (MODE == 0)
            acc[i][j] = __builtin_amdgcn_mfma_f32_16x16x32_bf16(af[i], bf[j], acc[i][j], 0, 0, 0);
          else
            acc[i][j] = __builtin_amdgcn_mfma_f32_16x16x32_f16(
                __builtin_bit_cast(half8v, af[i]), __builtin_bit_cast(half8v, bf[j]), acc[i][j], 0, 0, 0);
        }
    }
    __syncthreads();
  }

  int rl = lane >> 4, cl = lane & 15;
  for (int j = 0; j < 4; ++j) {
    int gn = bx * BN + wc * 64 + j * 16 + cl;
    for (int i = 0; i < 4; ++i) {
      for (int q = 0; q < 4; ++q) {
        int gm = by * BM + wr * 64 + i * 16 + rl * 4 + q;
        float v = acc[i][j][q];
        if constexpr (MODE == 0) {
          Cout[(size_t)gm * 512 + gn] = f16bits(v + bias[gn]);
        } else if constexpr (MODE == 1) {
          int bb = gm >> 7, s = gm & 127;
          Cout[(((size_t)(bb * 16 + (s >> 3)) * 512) + gn) * 8 + (s & 7)] = f16bits(v);
        } else {
          int tt = gm & 127, bb = gm >> 7;
          Cout[((size_t)tt * 64 + bb) * KX + 768 + gn] = f2bf(v);
        }
      }
    }
  }
}

// ---------- k_recur: r10 recurrence (blocks 0..63) + independent transposes
//            on the idle CUs (blocks 64..949) ----------
// blocks 64..693 : W_out [1280][8000] f32 -> WoT [8064][1280] bf16 (4 tiles each)
// blocks 694..949: enc [b][s][e] f32 -> encTh [b][e][s] f16       (4 tiles each)
#define STREAM4(PH) { \
  float a0 = 0, a1 = 0, a2 = 0, a3 = 0; \
  uint4 cb[8], nb[8]; \
  _Pragma("unroll") \
  for (int j = 0; j < 8; ++j) cb[j] = Wp[(size_t)j * 512]; \
  for (int blk = 0; blk < 4; ++blk) { \
    if (blk + 1 < 4) { \
      _Pragma("unroll") \
      for (int j = 0; j < 8; ++j) nb[j] = Wp[(size_t)((blk + 1) * 8 + j) * 512]; \
    } \
    _Pragma("unroll") \
    for (int j = 0; j < 8; ++j) { \
      uint4 wv = cb[j]; uint4 xv = hp4[hbase + blk * 8 + j]; \
      a0 = fdot2(wv.x, xv.x, a0); a1 = fdot2(wv.y, xv.y, a1); \
      a2 = fdot2(wv.z, xv.z, a2); a3 = fdot2(wv.w, xv.w, a3); \
    } \
    _Pragma("unroll") \
    for (int j = 0; j < 8; ++j) cb[j] = nb[j]; \
  } \
  ph[PH][mn] = (a0 + a1) + (a2 + a3); }

__global__ __launch_bounds__(1024) void k_recur(
    const float* __restrict__ We1,     // [1024][20]
    const float* __restrict__ be1,
    const float* __restrict__ We2,
    const float* __restrict__ be2,
    const uint4* __restrict__ W2,      // chunked f16, 32768 uint4
    const uint4* __restrict__ encW2,   // [64][16][512] uint4
    const unsigned short* __restrict__ Remb, // f16 [8192][512] (brnn folded)
    const float* __restrict__ E1g,     // [64][20][128]
    unsigned short* __restrict__ X,    // [8192][1280] bf16
    float* __restrict__ wout,          // [64][128][128]
    const float* __restrict__ Wo,      // [1280][8000]
    unsigned short* __restrict__ WoT,  // [8064][1280] bf16
    const float* __restrict__ enc,     // [64][128][512]
    unsigned short* __restrict__ encTh)// [64][512][128] f16
{
  __shared__ __align__(16) uint4 el[16][512];   // 128 KB: encW2 slice / transpose tile
  __shared__ uint32_t E1p[HE][SLEN / 2];        // 5 KB (f16 pairs)
  __shared__ uint32_t w1p[HE][257];             // 20.6 KB
  __shared__ uint32_t hpair[DECD / 2];          // 1 KB
  __shared__ uint32_t wpairS[SLEN / 2];         // 256 B
  __shared__ float ph[2][DECD];                 // 4 KB
  __shared__ float be1s[HE], w2s[HE];
  __shared__ float be2s;

  int bid = blockIdx.x, tid = threadIdx.x;

  if (bid >= 64) {
    // ---------- independent transposes, overlaid on el ----------
    float (*tile)[65] = (float(*)[65])el;
    if (bid < 694) {
      for (int q = 0; q < 4; ++q) {
        int t4 = (bid - 64) * 4 + q;
        int n0 = (t4 % 126) * 64, k0 = (t4 / 126) * 64;
        for (int i = tid; i < 4096; i += 1024) {
          int kk = i >> 6, nn = i & 63;
          int n = n0 + nn;
          tile[kk][nn] = (n < VOC) ? Wo[(size_t)(k0 + kk) * VOC + n] : 0.f;
        }
        __syncthreads();
        for (int i = tid; i < 4096; i += 1024) {
          int nn = i >> 6, kk = i & 63;
          WoT[(size_t)(n0 + nn) * KX + k0 + kk] = f2bf(tile[kk][nn]);
        }
        __syncthreads();
      }
    } else {
      for (int q = 0; q < 4; ++q) {
        int t4 = (bid - 694) * 4 + q;
        int eb_ = t4 >> 4;
        int e0 = ((t4 >> 1) & 7) * 64;
        int s0 = (t4 & 1) * 64;
        const float* ebp = enc + (size_t)eb_ * SLEN * ENCD;
        for (int i = tid; i < 4096; i += 1024) {
          int ss = i >> 6, ee = i & 63;
          tile[ss][ee] = ebp[(size_t)(s0 + ss) * ENCD + e0 + ee];
        }
        __syncthreads();
        unsigned short* ob = encTh + (size_t)eb_ * ENCD * SLEN;
        for (int i = tid; i < 4096; i += 1024) {
          int ee = i >> 6, ss = i & 63;
          ob[(size_t)(e0 + ee) * SLEN + s0 + ss] = f16bits(tile[ss][ee]);
        }
        __syncthreads();
      }
    }
    return;
  }

  // ---------- recurrence (r10, unchanged) ----------
  int b = bid;

  for (int i = tid; i < 16 * 512; i += 1024) ((uint4*)el)[i] = encW2[(size_t)b * 8192 + i];
  for (int i = tid; i < HE * (SLEN / 2); i += 1024) {
    int h = i >> 6, p = i & 63;
    const float* ebase = E1g + ((size_t)b * HE + h) * SLEN;
    ((uint32_t*)E1p)[i] = pkh2(ebase[2 * p], ebase[2 * p + 1]);
  }
  for (int i = tid; i < HE * 256; i += 1024) {
    int h = i >> 8, p = i & 255;
    w1p[h][p] = pkh2(We1[(size_t)(ENCD + 2 * p) * HE + h],
                     We1[(size_t)(ENCD + 2 * p + 1) * HE + h]);
  }
  for (int i = tid; i < DECD / 2; i += 1024) hpair[i] = 0;
  for (int i = tid; i < DECD; i += 1024) { ph[0][i] = 0.f; ph[1][i] = 0.f; }
  if (tid < HE) { be1s[tid] = be1[tid]; w2s[tid] = We2[tid]; }
  if (tid == 0) be2s = be2[0];
  __syncthreads();

  const int lane = tid & 63;
  const int wv_ = tid >> 6;
  int mn, mh0;
  if (tid < 448)      { mn = tid;        mh0 = 0; }
  else if (tid < 896) { mn = tid - 448;  mh0 = 1; }
  else if (tid < 960) { mn = 448 + lane; mh0 = 0; }   // wave 14
  else                { mn = 448 + lane; mh0 = 1; }   // wave 15 (after attn)
  const uint4* Wp = W2 + (size_t)(mh0 * 32) * 512 + mn;
  const uint4* hp4 = (const uint4*)hpair;
  const int hbase = mh0 * 32;

  // attention lane roles (wave 15)
  int ah = lane % 20, aseg = lane / 20;
  int q0 = aseg * 86;
  int q1 = (aseg == 2) ? 256 : q0 + 86;
  if (aseg >= 3) { q0 = 0; q1 = 0; }

  for (int t = 0; t < TLEN; ++t) {
    const int rowr = t * BATCH + b;
    float rpre = 0.f;

    if (wv_ < 15) {
      // ---------- phase A: stream (4 groups) ----------
      if (tid < 512) {
        union { unsigned short u; _Float16 f; } c;
        c.u = Remb[(size_t)rowr * 512 + tid];
        rpre = (float)c.f;
      }
      STREAM4(mh0)
    } else {
      // ---------- phase A: attention chain, raised priority ----------
      __builtin_amdgcn_s_setprio(1);
      float p0 = 0, p1 = 0;
      for (int q = q0; q < q1; q += 2) {
        p0 = fdot2(w1p[ah][q], hpair[q], p0);
        p1 = fdot2(w1p[ah][q + 1], hpair[q + 1], p1);
      }
      float p = p0 + p1;
      float pa = __shfl(p, lane + 20);
      float pb = __shfl(p, lane + 40);
      float edv = p + pa + pb + ((lane < HE) ? be1s[lane] : 0.f);
      float e0a = 0.f, e1a = 0.f;
      #pragma unroll
      for (int h = 0; h < HE; ++h) {
        union { uint32_t u; h2 hh; } e; e.u = E1p[h][lane];
        float ed = __shfl(edv, h);
        e0a += eluf((float)e.hh[0] + ed) * w2s[h];
        e1a += eluf((float)e.hh[1] + ed) * w2s[h];
      }
      float s0 = expf(eluf(e0a + be2s));
      float s1 = expf(eluf(e1a + be2s));
      float tot = s0 + s1;
      #pragma unroll
      for (int o = 1; o < 64; o <<= 1) tot += __shfl_xor(tot, o);
      float inv = 1.f / tot;
      float w0 = s0 * inv, w1 = s1 * inv;
      wpairS[lane] = pkh2(w0, w1);
      float2 wv2 = { w0, w1 };
      *(float2*)(wout + ((size_t)b * TLEN + t) * SLEN + 2 * lane) = wv2;
      __builtin_amdgcn_s_setprio(0);
      // ---------- then its share of the stream ----------
      STREAM4(1)
    }
    __syncthreads();

    // ---------- phase B: ctx (LDS) + combine ----------
    if (tid < 512) {
      int n = tid;
      float c0 = 0, c1 = 0, c2 = 0, c3 = 0;
      #pragma unroll
      for (int g = 0; g < 16; ++g) {
        uint4 ev = el[g][n];
        uint4 wv = ((const uint4*)wpairS)[g];
        c0 = fdot2(ev.x, wv.x, c0); c1 = fdot2(ev.y, wv.y, c1);
        c2 = fdot2(ev.z, wv.z, c2); c3 = fdot2(ev.w, wv.w, c3);
      }
      float v = rpre + ph[0][n] + ph[1][n] + (c0 + c1) + (c2 + c3);
      float aa = eluf(v);
      X[(size_t)rowr * KX + 256 + n] = f2bf(aa);
      float bb = __shfl_down(aa, 1);
      if (!(n & 1)) hpair[n >> 1] = pkh2(aa, bb);
    }
    __syncthreads();
  }
}

// ---------- k_gemm: out = elu(X @ WoT^T + b_out), M=8192 N=8000 K=1280 ----------
// linear grid 4032 = 63x64, bijective XCD swizzle (4032 % 8 == 0)
__global__ __launch_bounds__(256) void k_gemm(
    const unsigned short* __restrict__ Xb,
    const unsigned short* __restrict__ WoT,
    const float* __restrict__ bout,
    float* __restrict__ out)
{
  __shared__ __align__(16) unsigned short As[BM * BK];
  __shared__ __align__(16) unsigned short Bs[BN * BK];
  int bid = blockIdx.x;
  int swz = (bid & 7) * 504 + (bid >> 3);
  int bx = swz % 63;
  int by = swz / 63;
  int tid = threadIdx.x;
  int wid = tid >> 6, lane = tid & 63;
  int wr = wid >> 1, wc = wid & 1;

  f32x4 acc[4][4];
  for (int i = 0; i < 4; ++i)
    for (int j = 0; j < 4; ++j) acc[i][j] = (f32x4)0.f;

  const unsigned short* Abase = Xb + (size_t)by * BM * KX;
  const unsigned short* Bbase = WoT + (size_t)bx * BN * KX;

  for (int kt = 0; kt < KX / BK; ++kt) {
    for (int j = 0; j < 4; ++j) {
      int c = tid + j * 256;
      int r = c >> 3, c16 = c & 7;
      int sk = c16 ^ (r & 7);
      gload16(Abase + (size_t)r * KX + kt * BK + sk * 8, (char*)As + c * 16);
      gload16(Bbase + (size_t)r * KX + kt * BK + sk * 8, (char*)Bs + c * 16);
    }
    __syncthreads();
    for (int ks = 0; ks < 2; ++ks) {
      short8 af[4], bf[4];
      int kc = ks * 4 + (lane >> 4);
      for (int i = 0; i < 4; ++i) {
        int r = wr * 64 + i * 16 + (lane & 15);
        af[i] = *(const short8*)((const char*)As + r * 128 + ((kc ^ (r & 7)) * 16));
      }
      for (int j = 0; j < 4; ++j) {
        int r = wc * 64 + j * 16 + (lane & 15);
        bf[j] = *(const short8*)((const char*)Bs + r * 128 + ((kc ^ (r & 7)) * 16));
      }
      for (int i = 0; i < 4; ++i)
        for (int j = 0; j < 4; ++j)
          acc[i][j] = __builtin_amdgcn_mfma_f32_16x16x32_bf16(af[i], bf[j], acc[i][j], 0, 0, 0);
    }
    __syncthreads();
  }

  int rl = lane >> 4, cl = lane & 15;
  for (int j = 0; j < 4; ++j) {
    int gn = bx * BN + wc * 64 + j * 16 + cl;
    if (gn >= VOC) continue;
    float bv = bout[gn];
    for (int i = 0; i < 4; ++i) {
      for (int q = 0; q < 4; ++q) {
        int gm = by * BM + wr * 64 + i * 16 + rl * 4 + q;
        int tt = gm >> 6, bb = gm & 63;
        float v = acc[i][j][q] + bv;
        v = v > 0.f ? v : (expf(v) - 1.f);
        out[((size_t)bb * TLEN + tt) * VOC + gn] = v;
      }
    }
  }
}

// ---------- launch ----------
extern "C" void kernel_launch(void* const* d_in, const int* in_sizes, int n_in,
                              void* d_out, int out_size, void* d_ws, size_t ws_size,
                              hipStream_t stream) {
  const float* enc  = (const float*)d_in[0];
  const int*   ro   = (const int*)d_in[1];
  const float* We1  = (const float*)d_in[2];
  const float* be1  = (const float*)d_in[3];
  const float* We2  = (const float*)d_in[4];
  const float* be2  = (const float*)d_in[5];
  const float* emb  = (const float*)d_in[6];
  const float* Wr   = (const float*)d_in[7];
  const float* brnn = (const float*)d_in[8];
  const float* Wo   = (const float*)d_in[9];
  const float* bo   = (const float*)d_in[10];

  char* ws = (char*)d_ws;
  unsigned short* X     = (unsigned short*)(ws);                 // 20,971,520
  unsigned short* WoT   = (unsigned short*)(ws + 20971520);      // 20,643,840
  unsigned short* W2    = (unsigned short*)(ws + 41615360);      //    524,288
  unsigned short* WembT = (unsigned short*)(ws + 42139648);      //    262,144
  unsigned short* WctxT = (unsigned short*)(ws + 42401792);      //    524,288
  unsigned short* ench  = (unsigned short*)(ws + 42926080);      //  8,388,608  (reused: encTh)
  float*          E1    = (float*)(ws + 51314688);               //    655,360
  unsigned short* Remb  = (unsigned short*)(ws + 51970048);      //  8,388,608  (reused: wh)
  unsigned short* encW2 = (unsigned short*)(ws + 60358656);      //  8,388,608
  unsigned short* encTh = ench;
  unsigned short* wh    = Remb;

  float* outs = (float*)d_out;
  float* wout = (float*)d_out + (size_t)BATCH * TLEN * VOC;

  // parallel precompute (merged)
  k_pre1 <<<dim3(14336),  256, 0, stream>>>(ro, emb, X, enc, ench, We1, E1);
  k_pre2 <<<dim3(1120),   256, 0, stream>>>(Wr, WembT, WctxT, W2);
  k_gs<0><<<dim3(4, 64),  256, 0, stream>>>(X, WembT, brnn, Remb);
  k_gs<1><<<dim3(4, 64),  256, 0, stream>>>(ench, WctxT, brnn, encW2);
  // sequential core + independent transposes on idle CUs
  k_recur<<<dim3(950),   1024, 0, stream>>>(We1, be1, We2, be2,
                                            (const uint4*)W2, (const uint4*)encW2,
                                            Remb, E1, X, wout,
                                            Wo, WoT, enc, encTh);
  // post: ctx fill + big GEMM
  k_wh   <<<dim3(1024),   256, 0, stream>>>(wout, wh);
  k_gs<2><<<dim3(4, 64),  256, 0, stream>>>(wh, encTh, brnn, X);
  k_gemm <<<dim3(4032),   256, 0, stream>>>(X, WoT, bo, outs);
  (void)in_sizes; (void)n_in; (void)out_size; (void)ws_size;
}

// Round 14
// 1189.618 us; speedup vs baseline: 2.2236x; 1.0558x over previous
//
#include <hip/hip_runtime.h>
#include <hip/hip_bf16.h>
#include <stdint.h>

#define BATCH 64
#define SLEN 128
#define TLEN 128
#define ENCD 512
#define DECD 512
#define EMBD 256
#define VOC  8000
#define HE   20
#define KX   1280      // EMB + DEC + ENC
#define NP2  8192      // VOC padded to 32*256

typedef __attribute__((ext_vector_type(8))) short short8;
typedef __attribute__((ext_vector_type(8))) _Float16 half8v;
typedef __attribute__((ext_vector_type(4))) float f32x4;
typedef _Float16 h2 __attribute__((ext_vector_type(2)));

// ---------- helpers ----------
__device__ inline unsigned short f2bf(float f) {
  union { float f; uint32_t u; } v; v.f = f;
  uint32_t r = v.u + 0x7fff + ((v.u >> 16) & 1);
  return (unsigned short)(r >> 16);
}
__device__ inline unsigned short f16bits(float f) {
  union { _Float16 h; unsigned short u; } c; c.h = (_Float16)f; return c.u;
}
__device__ inline uint32_t pkh2(float a, float b) {
  union { h2 h; uint32_t u; } v;
  v.h = h2{(_Float16)a, (_Float16)b};
  return v.u;
}
__device__ inline float fdot2(uint32_t a, uint32_t b, float c) {
#if __has_builtin(__builtin_amdgcn_fdot2)
  union { uint32_t u; h2 h; } x, y; x.u = a; y.u = b;
  return __builtin_amdgcn_fdot2(x.h, y.h, c, false);
#else
  union { uint32_t u; h2 h; } x, y; x.u = a; y.u = b;
  return c + (float)x.h[0] * (float)y.h[0] + (float)x.h[1] * (float)y.h[1];
#endif
}
__device__ inline float eluf(float x) { return x > 0.f ? x : (expf(x) - 1.f); }

typedef const __attribute__((address_space(1))) unsigned int* gptr_t;
typedef __attribute__((address_space(3))) unsigned int* lptr_t;
__device__ inline void gload16(const void* g, void* l) {
  __builtin_amdgcn_global_load_lds((gptr_t)g, (lptr_t)l, 16, 0, 0);
}

// ---------- k_pre1: merged k_lc / k_ench / k_e1 ----------
__global__ __launch_bounds__(256) void k_pre1(const int* __restrict__ ro,
                                              const float* __restrict__ emb,
                                              unsigned short* __restrict__ X,
                                              const float* __restrict__ enc,
                                              unsigned short* __restrict__ ench,
                                              const float* __restrict__ We1,
                                              float* __restrict__ E1) {
  __shared__ float rowbuf[4][ENCD];
  __shared__ float part[4][HE][2];
  int bid = blockIdx.x, tid = threadIdx.x;
  if (bid < 8192) {
    int r = bid;
    int t = r >> 6, b = r & 63;
    int lc = (t == 0) ? 0 : ro[b * TLEN + t - 1];
    lc = ((lc % VOC) + VOC) % VOC;
    X[(size_t)r * KX + tid] = f2bf(emb[(size_t)lc * EMBD + tid]);
  } else if (bid < 12288) {
    int i = ((bid - 8192) * 256 + tid) * 4;
    float4 v = *(const float4*)(enc + i);
    ushort4 o = { f16bits(v.x), f16bits(v.y), f16bits(v.z), f16bits(v.w) };
    *(ushort4*)(ench + i) = o;
  } else {
    int r0 = (bid - 12288) * 4;
    for (int i = tid; i < 4 * ENCD; i += 256) {
      int rl = i >> 9, e = i & 511;
      rowbuf[rl][e] = enc[(size_t)(r0 + rl) * ENCD + e];
    }
    __syncthreads();
    if (tid < 160) {
      int kg = tid / 80, rem = tid % 80, rl = rem / 20, h = rem % 20;
      float acc = 0.f;
      for (int k = kg * 256; k < kg * 256 + 256; ++k)
        acc += rowbuf[rl][k] * We1[k * HE + h];
      part[rl][h][kg] = acc;
    }
    __syncthreads();
    if (tid < 80) {
      int rl = tid / 20, h = tid % 20;
      int r = r0 + rl, bb = r >> 7, ss = r & 127;
      E1[((size_t)bb * HE + h) * SLEN + ss] = part[rl][h][0] + part[rl][h][1];
    }
  }
}

// ---------- k_pre2: merged k_tr_w(WembT) / k_tr_w(WctxT) / k_prep_wr ----------
__global__ __launch_bounds__(256) void k_pre2(const float* __restrict__ Wr,
                                              unsigned short* __restrict__ WembT,
                                              unsigned short* __restrict__ WctxT,
                                              unsigned short* __restrict__ W2) {
  __shared__ float tile[64][65];
  int bid = blockIdx.x, tid = threadIdx.x;
  if (bid < 96) {
    int k0, KN, fmt, bx, by;
    unsigned short* dst;
    if (bid < 32) { k0 = 0;   KN = 256; fmt = 1; bx = bid & 7; by = bid >> 3; dst = WembT; }
    else          { int id2 = bid - 32; k0 = 768; KN = 512; fmt = 0; bx = id2 & 7; by = id2 >> 3; dst = WctxT; }
    int n0 = bx * 64, kt = by * 64;
    for (int i = tid; i < 4096; i += 256) {
      int kk = i >> 6, nn = i & 63;
      tile[kk][nn] = Wr[(size_t)(k0 + kt + kk) * 512 + n0 + nn];
    }
    __syncthreads();
    for (int i = tid; i < 4096; i += 256) {
      int nn = i >> 6, kk = i & 63;
      float v = tile[kk][nn];
      dst[(size_t)(n0 + nn) * KN + kt + kk] = fmt ? f2bf(v) : f16bits(v);
    }
  } else {
    int i = (bid - 96) * 256 + tid;
    int n = i & 511;
    int j = (i >> 9) & 7;
    int kc = (i >> 12) & 31;
    int h = (i >> 17) & 1;
    int k = h * 256 + kc * 8 + j;
    W2[(((size_t)(h * 32 + kc) * 512) + n) * 8 + j] = f16bits(Wr[(size_t)(256 + k) * 512 + n]);
  }
}

// ---------- k_wh: wout f32 [8192][128] -> f16 ----------
__global__ __launch_bounds__(256) void k_wh(const float* __restrict__ wout,
                                            unsigned short* __restrict__ wh) {
  int i = (blockIdx.x * 256 + threadIdx.x) * 4;
  float4 v = *(const float4*)(wout + i);
  ushort4 o = { f16bits(v.x), f16bits(v.y), f16bits(v.z), f16bits(v.w) };
  *(ushort4*)(wh + i) = o;
}

// ---------- k_gs<MODE>: 128x128xK MFMA GEMM ----------
#define BM 128
#define BN 128
#define BK 64

template<int MODE>
__global__ __launch_bounds__(256) void k_gs(
    const unsigned short* __restrict__ A,
    const unsigned short* __restrict__ B,
    const float* __restrict__ bias,
    unsigned short* __restrict__ Cout)
{
  constexpr int As = (MODE == 0) ? KX : (MODE == 1 ? 512 : 128);
  constexpr int Bs = (MODE == 0) ? 256 : (MODE == 1 ? 512 : 128);
  constexpr int KT = (MODE == 0) ? 4 : (MODE == 1 ? 8 : 2);
  __shared__ __align__(16) unsigned short Asd[BM * BK];
  __shared__ __align__(16) unsigned short Bsd[BN * BK];
  int bx = blockIdx.x, by = blockIdx.y;
  int tid = threadIdx.x;
  int wid = tid >> 6, lane = tid & 63;
  int wr = wid >> 1, wc = wid & 1;

  f32x4 acc[4][4];
  for (int i = 0; i < 4; ++i)
    for (int j = 0; j < 4; ++j) acc[i][j] = (f32x4)0.f;

  const unsigned short* Abase = A + (size_t)by * BM * As;
  const unsigned short* Bbase = B + (size_t)bx * BN * Bs + (MODE == 2 ? (size_t)by * 512 * 128 : 0);

  for (int kt = 0; kt < KT; ++kt) {
    for (int j = 0; j < 4; ++j) {
      int c = tid + j * 256;
      int r = c >> 3, c16 = c & 7;
      int sk = c16 ^ (r & 7);
      gload16(Abase + (size_t)r * As + kt * BK + sk * 8, (char*)Asd + c * 16);
      gload16(Bbase + (size_t)r * Bs + kt * BK + sk * 8, (char*)Bsd + c * 16);
    }
    __syncthreads();
    for (int ks = 0; ks < 2; ++ks) {
      short8 af[4], bf[4];
      int kc = ks * 4 + (lane >> 4);
      for (int i = 0; i < 4; ++i) {
        int r = wr * 64 + i * 16 + (lane & 15);
        af[i] = *(const short8*)((const char*)Asd + r * 128 + ((kc ^ (r & 7)) * 16));
      }
      for (int j = 0; j < 4; ++j) {
        int r = wc * 64 + j * 16 + (lane & 15);
        bf[j] = *(const short8*)((const char*)Bsd + r * 128 + ((kc ^ (r & 7)) * 16));
      }
      for (int i = 0; i < 4; ++i)
        for (int j = 0; j < 4; ++j) {
          if constexpr (MODE == 0)
            acc[i][j] = __builtin_amdgcn_mfma_f32_16x16x32_bf16(af[i], bf[j], acc[i][j], 0, 0, 0);
          else
            acc[i][j] = __builtin_amdgcn_mfma_f32_16x16x32_f16(
                __builtin_bit_cast(half8v, af[i]), __builtin_bit_cast(half8v, bf[j]), acc[i][j], 0, 0, 0);
        }
    }
    __syncthreads();
  }

  int rl = lane >> 4, cl = lane & 15;
  for (int j = 0; j < 4; ++j) {
    int gn = bx * BN + wc * 64 + j * 16 + cl;
    for (int i = 0; i < 4; ++i) {
      for (int q = 0; q < 4; ++q) {
        int gm = by * BM + wr * 64 + i * 16 + rl * 4 + q;
        float v = acc[i][j][q];
        if constexpr (MODE == 0) {
          Cout[(size_t)gm * 512 + gn] = f16bits(v + bias[gn]);
        } else if constexpr (MODE == 1) {
          int bb = gm >> 7, s = gm & 127;
          Cout[(((size_t)(bb * 16 + (s >> 3)) * 512) + gn) * 8 + (s & 7)] = f16bits(v);
        } else {
          int tt = gm & 127, bb = gm >> 7;
          Cout[((size_t)tt * 64 + bb) * KX + 768 + gn] = f2bf(v);
        }
      }
    }
  }
}

// ---------- k_recur: r10 recurrence (blocks 0..63) + independent transposes ----------
// blocks 64..703 : W_out [1280][8000] f32 -> WoT [8192][1280] bf16 (zero-pad, 4 tiles each)
// blocks 704..959: enc [b][s][e] f32 -> encTh [b][e][s] f16       (4 tiles each)
#define STREAM4(PH) { \
  float a0 = 0, a1 = 0, a2 = 0, a3 = 0; \
  uint4 cb[8], nb[8]; \
  _Pragma("unroll") \
  for (int j = 0; j < 8; ++j) cb[j] = Wp[(size_t)j * 512]; \
  for (int blk = 0; blk < 4; ++blk) { \
    if (blk + 1 < 4) { \
      _Pragma("unroll") \
      for (int j = 0; j < 8; ++j) nb[j] = Wp[(size_t)((blk + 1) * 8 + j) * 512]; \
    } \
    _Pragma("unroll") \
    for (int j = 0; j < 8; ++j) { \
      uint4 wv = cb[j]; uint4 xv = hp4[hbase + blk * 8 + j]; \
      a0 = fdot2(wv.x, xv.x, a0); a1 = fdot2(wv.y, xv.y, a1); \
      a2 = fdot2(wv.z, xv.z, a2); a3 = fdot2(wv.w, xv.w, a3); \
    } \
    _Pragma("unroll") \
    for (int j = 0; j < 8; ++j) cb[j] = nb[j]; \
  } \
  ph[PH][mn] = (a0 + a1) + (a2 + a3); }

__global__ __launch_bounds__(1024) void k_recur(
    const float* __restrict__ We1,
    const float* __restrict__ be1,
    const float* __restrict__ We2,
    const float* __restrict__ be2,
    const uint4* __restrict__ W2,
    const uint4* __restrict__ encW2,
    const unsigned short* __restrict__ Remb,
    const float* __restrict__ E1g,
    unsigned short* __restrict__ X,
    float* __restrict__ wout,
    const float* __restrict__ Wo,
    unsigned short* __restrict__ WoT,
    const float* __restrict__ enc,
    unsigned short* __restrict__ encTh)
{
  __shared__ __align__(16) uint4 el[16][512];
  __shared__ uint32_t E1p[HE][SLEN / 2];
  __shared__ uint32_t w1p[HE][257];
  __shared__ uint32_t hpair[DECD / 2];
  __shared__ uint32_t wpairS[SLEN / 2];
  __shared__ float ph[2][DECD];
  __shared__ float be1s[HE], w2s[HE];
  __shared__ float be2s;

  int bid = blockIdx.x, tid = threadIdx.x;

  if (bid >= 64) {
    float (*tile)[65] = (float(*)[65])el;
    if (bid < 704) {
      for (int q = 0; q < 4; ++q) {
        int t4 = (bid - 64) * 4 + q;
        int n0 = (t4 % 128) * 64, k0 = (t4 / 128) * 64;
        for (int i = tid; i < 4096; i += 1024) {
          int kk = i >> 6, nn = i & 63;
          int n = n0 + nn;
          tile[kk][nn] = (n < VOC) ? Wo[(size_t)(k0 + kk) * VOC + n] : 0.f;
        }
        __syncthreads();
        for (int i = tid; i < 4096; i += 1024) {
          int nn = i >> 6, kk = i & 63;
          WoT[(size_t)(n0 + nn) * KX + k0 + kk] = f2bf(tile[kk][nn]);
        }
        __syncthreads();
      }
    } else {
      for (int q = 0; q < 4; ++q) {
        int t4 = (bid - 704) * 4 + q;
        int eb_ = t4 >> 4;
        int e0 = ((t4 >> 1) & 7) * 64;
        int s0 = (t4 & 1) * 64;
        const float* ebp = enc + (size_t)eb_ * SLEN * ENCD;
        for (int i = tid; i < 4096; i += 1024) {
          int ss = i >> 6, ee = i & 63;
          tile[ss][ee] = ebp[(size_t)(s0 + ss) * ENCD + e0 + ee];
        }
        __syncthreads();
        unsigned short* ob = encTh + (size_t)eb_ * ENCD * SLEN;
        for (int i = tid; i < 4096; i += 1024) {
          int ee = i >> 6, ss = i & 63;
          ob[(size_t)(e0 + ee) * SLEN + s0 + ss] = f16bits(tile[ss][ee]);
        }
        __syncthreads();
      }
    }
    return;
  }

  int b = bid;

  for (int i = tid; i < 16 * 512; i += 1024) ((uint4*)el)[i] = encW2[(size_t)b * 8192 + i];
  for (int i = tid; i < HE * (SLEN / 2); i += 1024) {
    int h = i >> 6, p = i & 63;
    const float* ebase = E1g + ((size_t)b * HE + h) * SLEN;
    ((uint32_t*)E1p)[i] = pkh2(ebase[2 * p], ebase[2 * p + 1]);
  }
  for (int i = tid; i < HE * 256; i += 1024) {
    int h = i >> 8, p = i & 255;
    w1p[h][p] = pkh2(We1[(size_t)(ENCD + 2 * p) * HE + h],
                     We1[(size_t)(ENCD + 2 * p + 1) * HE + h]);
  }
  for (int i = tid; i < DECD / 2; i += 1024) hpair[i] = 0;
  for (int i = tid; i < DECD; i += 1024) { ph[0][i] = 0.f; ph[1][i] = 0.f; }
  if (tid < HE) { be1s[tid] = be1[tid]; w2s[tid] = We2[tid]; }
  if (tid == 0) be2s = be2[0];
  __syncthreads();

  const int lane = tid & 63;
  const int wv_ = tid >> 6;
  int mn, mh0;
  if (tid < 448)      { mn = tid;        mh0 = 0; }
  else if (tid < 896) { mn = tid - 448;  mh0 = 1; }
  else if (tid < 960) { mn = 448 + lane; mh0 = 0; }
  else                { mn = 448 + lane; mh0 = 1; }
  const uint4* Wp = W2 + (size_t)(mh0 * 32) * 512 + mn;
  const uint4* hp4 = (const uint4*)hpair;
  const int hbase = mh0 * 32;

  int ah = lane % 20, aseg = lane / 20;
  int q0 = aseg * 86;
  int q1 = (aseg == 2) ? 256 : q0 + 86;
  if (aseg >= 3) { q0 = 0; q1 = 0; }

  for (int t = 0; t < TLEN; ++t) {
    const int rowr = t * BATCH + b;
    float rpre = 0.f;

    if (wv_ < 15) {
      if (tid < 512) {
        union { unsigned short u; _Float16 f; } c;
        c.u = Remb[(size_t)rowr * 512 + tid];
        rpre = (float)c.f;
      }
      STREAM4(mh0)
    } else {
      __builtin_amdgcn_s_setprio(1);
      float p0 = 0, p1 = 0;
      for (int q = q0; q < q1; q += 2) {
        p0 = fdot2(w1p[ah][q], hpair[q], p0);
        p1 = fdot2(w1p[ah][q + 1], hpair[q + 1], p1);
      }
      float p = p0 + p1;
      float pa = __shfl(p, lane + 20);
      float pb = __shfl(p, lane + 40);
      float edv = p + pa + pb + ((lane < HE) ? be1s[lane] : 0.f);
      float e0a = 0.f, e1a = 0.f;
      #pragma unroll
      for (int h = 0; h < HE; ++h) {
        union { uint32_t u; h2 hh; } e; e.u = E1p[h][lane];
        float ed = __shfl(edv, h);
        e0a += eluf((float)e.hh[0] + ed) * w2s[h];
        e1a += eluf((float)e.hh[1] + ed) * w2s[h];
      }
      float s0 = expf(eluf(e0a + be2s));
      float s1 = expf(eluf(e1a + be2s));
      float tot = s0 + s1;
      #pragma unroll
      for (int o = 1; o < 64; o <<= 1) tot += __shfl_xor(tot, o);
      float inv = 1.f / tot;
      float w0 = s0 * inv, w1 = s1 * inv;
      wpairS[lane] = pkh2(w0, w1);
      float2 wv2 = { w0, w1 };
      *(float2*)(wout + ((size_t)b * TLEN + t) * SLEN + 2 * lane) = wv2;
      __builtin_amdgcn_s_setprio(0);
      STREAM4(1)
    }
    __syncthreads();

    if (tid < 512) {
      int n = tid;
      float c0 = 0, c1 = 0, c2 = 0, c3 = 0;
      #pragma unroll
      for (int g = 0; g < 16; ++g) {
        uint4 ev = el[g][n];
        uint4 wv = ((const uint4*)wpairS)[g];
        c0 = fdot2(ev.x, wv.x, c0); c1 = fdot2(ev.y, wv.y, c1);
        c2 = fdot2(ev.z, wv.z, c2); c3 = fdot2(ev.w, wv.w, c3);
      }
      float v = rpre + ph[0][n] + ph[1][n] + (c0 + c1) + (c2 + c3);
      float aa = eluf(v);
      X[(size_t)rowr * KX + 256 + n] = f2bf(aa);
      float bb = __shfl_down(aa, 1);
      if (!(n & 1)) hpair[n >> 1] = pkh2(aa, bb);
    }
    __syncthreads();
  }
}

// ---------- k_gemm: 256x256 8-wave, double-buffered LDS, counted vmcnt ----------
// M=8192, N=8192 (WoT zero-padded), K=1280. 512 threads = 8 waves (2 Mrow x 4 Ncol);
// per-wave output 128x64; LDS 128 KB (2 x (256x64 A + 256x64 B) bf16).
#define GSTAGE(KT, C) { _Pragma("unroll") \
  for (int j5 = 0; j5 < 4; ++j5) { \
    int c4 = tid + j5 * 512; \
    int r5 = c4 >> 3, c16 = c4 & 7; \
    int sk = c16 ^ (r5 & 7); \
    gload16(Abase + (size_t)r5 * KX + (KT) * 64 + sk * 8, (char*)Ah[C] + c4 * 16); \
  } \
  _Pragma("unroll") \
  for (int j5 = 0; j5 < 4; ++j5) { \
    int c4 = tid + j5 * 512; \
    int r5 = c4 >> 3, c16 = c4 & 7; \
    int sk = c16 ^ (r5 & 7); \
    gload16(Bbase + (size_t)r5 * KX + (KT) * 64 + sk * 8, (char*)Bh[C] + c4 * 16); \
  } }

__global__ __launch_bounds__(512) void k_gemm(
    const unsigned short* __restrict__ Xb,
    const unsigned short* __restrict__ WoT,   // [8192][1280] bf16 (zero-padded)
    const float* __restrict__ bout,
    float* __restrict__ out)
{
  __shared__ __align__(16) unsigned short Ah[2][256 * 64];  // 64 KB
  __shared__ __align__(16) unsigned short Bh[2][256 * 64];  // 64 KB
  int bid = blockIdx.x;
  int swz = (bid & 7) * 128 + (bid >> 3);   // 1024 blocks, bijective XCD swizzle
  int by = swz >> 5, bx = swz & 31;
  int tid = threadIdx.x;
  int lane = tid & 63;
  int wid = tid >> 6;
  int wrow = wid >> 2, wcol = wid & 3;

  const unsigned short* Abase = Xb + (size_t)by * 256 * KX;
  const unsigned short* Bbase = WoT + (size_t)bx * 256 * KX;

  f32x4 acc[8][4];
  #pragma unroll
  for (int i = 0; i < 8; ++i)
    #pragma unroll
    for (int j = 0; j < 4; ++j) acc[i][j] = (f32x4)0.f;

  GSTAGE(0, 0)
  GSTAGE(1, 1)
  asm volatile("s_waitcnt vmcnt(8)" ::: "memory");
  __builtin_amdgcn_s_barrier();
  __builtin_amdgcn_sched_barrier(0);

  for (int kt = 0; kt < 20; ++kt) {
    int c = kt & 1;
    const char* Ab = (const char*)Ah[c];
    const char* Bb = (const char*)Bh[c];
    short8 af[4][2], bf[4][2];
    // fragments: A rows wrow*128 + 0..63, B all 4 col-frags
    #pragma unroll
    for (int i = 0; i < 4; ++i)
      #pragma unroll
      for (int ks = 0; ks < 2; ++ks) {
        int rw = wrow * 128 + i * 16 + (lane & 15);
        int kc = ks * 4 + (lane >> 4);
        af[i][ks] = *(const short8*)(Ab + rw * 128 + ((kc ^ (rw & 7)) * 16));
      }
    #pragma unroll
    for (int j = 0; j < 4; ++j)
      #pragma unroll
      for (int ks = 0; ks < 2; ++ks) {
        int rb = wcol * 64 + j * 16 + (lane & 15);
        int kc = ks * 4 + (lane >> 4);
        bf[j][ks] = *(const short8*)(Bb + rb * 128 + ((kc ^ (rb & 7)) * 16));
      }
    // q0+q1: rows i0-3, all cols
    __builtin_amdgcn_s_setprio(1);
    #pragma unroll
    for (int i = 0; i < 4; ++i)
      #pragma unroll
      for (int j = 0; j < 4; ++j)
        #pragma unroll
        for (int ks = 0; ks < 2; ++ks)
          acc[i][j] = __builtin_amdgcn_mfma_f32_16x16x32_bf16(af[i][ks], bf[j][ks], acc[i][j], 0, 0, 0);
    __builtin_amdgcn_s_setprio(0);
    // reload af with rows 64..127
    #pragma unroll
    for (int i = 0; i < 4; ++i)
      #pragma unroll
      for (int ks = 0; ks < 2; ++ks) {
        int rw = wrow * 128 + 64 + i * 16 + (lane & 15);
        int kc = ks * 4 + (lane >> 4);
        af[i][ks] = *(const short8*)(Ab + rw * 128 + ((kc ^ (rw & 7)) * 16));
      }
    // q2: rows i4-7, cols j0-1
    __builtin_amdgcn_s_setprio(1);
    #pragma unroll
    for (int i = 0; i < 4; ++i)
      #pragma unroll
      for (int j = 0; j < 2; ++j)
        #pragma unroll
        for (int ks = 0; ks < 2; ++ks)
          acc[4 + i][j] = __builtin_amdgcn_mfma_f32_16x16x32_bf16(af[i][ks], bf[j][ks], acc[4 + i][j], 0, 0, 0);
    __builtin_amdgcn_s_setprio(0);
    // all LDS reads of buffer c are done block-wide -> safe to overwrite
    __builtin_amdgcn_s_barrier();
    __builtin_amdgcn_sched_barrier(0);
    if (kt < 18) GSTAGE(kt + 2, c)
    // q3: rows i4-7, cols j2-3 (overlaps staging issue latency)
    __builtin_amdgcn_s_setprio(1);
    #pragma unroll
    for (int i = 0; i < 4; ++i)
      #pragma unroll
      for (int j = 0; j < 2; ++j)
        #pragma unroll
        for (int ks = 0; ks < 2; ++ks)
          acc[4 + i][2 + j] = __builtin_amdgcn_mfma_f32_16x16x32_bf16(af[i][ks], bf[2 + j][ks], acc[4 + i][2 + j], 0, 0, 0);
    __builtin_amdgcn_s_setprio(0);
    if (kt < 18) { asm volatile("s_waitcnt vmcnt(8)" ::: "memory"); }
    else         { asm volatile("s_waitcnt vmcnt(0)" ::: "memory"); }
    __builtin_amdgcn_s_barrier();
    __builtin_amdgcn_sched_barrier(0);
  }

  int rl = lane >> 4, cl = lane & 15;
  #pragma unroll
  for (int j = 0; j < 4; ++j) {
    int gn = bx * 256 + wcol * 64 + j * 16 + cl;
    if (gn >= VOC) continue;
    float bv = bout[gn];
    #pragma unroll
    for (int i = 0; i < 8; ++i) {
      #pragma unroll
      for (int q = 0; q < 4; ++q) {
        int gm = by * 256 + wrow * 128 + i * 16 + rl * 4 + q;
        int tt = gm >> 6, bb = gm & 63;
        float v = acc[i][j][q] + bv;
        v = v > 0.f ? v : (expf(v) - 1.f);
        out[((size_t)bb * TLEN + tt) * VOC + gn] = v;
      }
    }
  }
}

// ---------- launch ----------
extern "C" void kernel_launch(void* const* d_in, const int* in_sizes, int n_in,
                              void* d_out, int out_size, void* d_ws, size_t ws_size,
                              hipStream_t stream) {
  const float* enc  = (const float*)d_in[0];
  const int*   ro   = (const int*)d_in[1];
  const float* We1  = (const float*)d_in[2];
  const float* be1  = (const float*)d_in[3];
  const float* We2  = (const float*)d_in[4];
  const float* be2  = (const float*)d_in[5];
  const float* emb  = (const float*)d_in[6];
  const float* Wr   = (const float*)d_in[7];
  const float* brnn = (const float*)d_in[8];
  const float* Wo   = (const float*)d_in[9];
  const float* bo   = (const float*)d_in[10];

  char* ws = (char*)d_ws;
  unsigned short* X     = (unsigned short*)(ws);                 // 20,971,520
  unsigned short* WoT   = (unsigned short*)(ws + 20971520);      // 20,971,520 (8192 rows)
  unsigned short* W2    = (unsigned short*)(ws + 41943040);      //    524,288
  unsigned short* WembT = (unsigned short*)(ws + 42467328);      //    262,144
  unsigned short* WctxT = (unsigned short*)(ws + 42729472);      //    524,288
  unsigned short* ench  = (unsigned short*)(ws + 43253760);      //  8,388,608 (reused: encTh)
  float*          E1    = (float*)(ws + 51642368);               //    655,360
  unsigned short* Remb  = (unsigned short*)(ws + 52297728);      //  8,388,608 (reused: wh)
  unsigned short* encW2 = (unsigned short*)(ws + 60686336);      //  8,388,608
  unsigned short* encTh = ench;
  unsigned short* wh    = Remb;

  float* outs = (float*)d_out;
  float* wout = (float*)d_out + (size_t)BATCH * TLEN * VOC;

  k_pre1 <<<dim3(14336),  256, 0, stream>>>(ro, emb, X, enc, ench, We1, E1);
  k_pre2 <<<dim3(1120),   256, 0, stream>>>(Wr, WembT, WctxT, W2);
  k_gs<0><<<dim3(4, 64),  256, 0, stream>>>(X, WembT, brnn, Remb);
  k_gs<1><<<dim3(4, 64),  256, 0, stream>>>(ench, WctxT, brnn, encW2);
  k_recur<<<dim3(960),   1024, 0, stream>>>(We1, be1, We2, be2,
                                            (const uint4*)W2, (const uint4*)encW2,
                                            Remb, E1, X, wout,
                                            Wo, WoT, enc, encTh);
  k_wh   <<<dim3(1024),   256, 0, stream>>>(wout, wh);
  k_gs<2><<<dim3(4, 64),  256, 0, stream>>>(wh, encTh, brnn, X);
  k_gemm <<<dim3(1024),   512, 0, stream>>>(X, WoT, bo, outs);
  (void)in_sizes; (void)n_in; (void)out_size; (void)ws_size;
}